// Round 1
// baseline (328.578 us; speedup 1.0000x reference)
//
#include <hip/hip_runtime.h>

#define T_LEN 2048
#define BSZ 4
#define NHEAD 16
#define DHEAD 64
#define DMODEL 1024
#define SCALE 0.125f
#define L2E_SCALE (0.125f * 1.44269504f)   // SCALE*log2(e): folded into Q at projection
#define ROW 72   // padded LDS row stride in bf16 (attn kernel)

typedef __bf16 bf16x8 __attribute__((ext_vector_type(8)));
typedef float f32x4 __attribute__((ext_vector_type(4)));

__device__ __forceinline__ float bf2f(unsigned short u) {
  union { unsigned int i; float f; } v; v.i = ((unsigned int)u) << 16; return v.f;
}
__device__ __forceinline__ unsigned short f2bf(float f) {
  union { float f; unsigned int i; } v; v.f = f;
  unsigned int r = v.i + 0x7fffu + ((v.i >> 16) & 1u);   // RNE
  return (unsigned short)(r >> 16);
}

typedef __attribute__((address_space(1))) void* gptr_t;
typedef __attribute__((address_space(3))) void* lptr_t;

__device__ __forceinline__ void load_lds16(const void* g, void* l) {
  __builtin_amdgcn_global_load_lds((gptr_t)g, (lptr_t)l, 16, 0, 0);
}

// ---- fused fp32->bf16 conversion (blocks 0..12287) + mask prep (block 12288) ----
__global__ __launch_bounds__(256) void cvt_prep(const float* __restrict__ h,
                                                const float* __restrict__ wq,
                                                const float* __restrict__ wkv,
                                                const float* __restrict__ wo,
                                                const unsigned char* __restrict__ mask,
                                                unsigned short* __restrict__ h_bf,
                                                unsigned short* __restrict__ wq_bf,
                                                unsigned short* __restrict__ wkv_bf,
                                                unsigned short* __restrict__ wo_bf,
                                                int* __restrict__ pos,
                                                int* __restrict__ nkeys) {
  const int tid = threadIdx.x;
  if (blockIdx.x < 12288) {
    const size_t E4 = (size_t)T_LEN * BSZ * DMODEL / 4;
    const size_t W4 = (size_t)NHEAD * DHEAD * DMODEL / 4;
    const size_t g = (size_t)blockIdx.x * 256 + tid;
    const float* src; unsigned short* dst; size_t off;
    if (g < E4)                { src = h;   dst = h_bf;   off = g; }
    else if (g < E4 + W4)      { src = wq;  dst = wq_bf;  off = g - E4; }
    else if (g < E4 + 3 * W4)  { src = wkv; dst = wkv_bf; off = g - E4 - W4; }
    else                       { src = wo;  dst = wo_bf;  off = g - E4 - 3 * W4; }
    const float4 v = *(const float4*)(src + off * 4);
    ushort4 o;
    o.x = f2bf(v.x); o.y = f2bf(v.y); o.z = f2bf(v.z); o.w = f2bf(v.w);
    *(ushort4*)(dst + off * 4) = o;
    return;
  }
  __shared__ int s_any;
  if (tid == 0) s_any = 0;
  __syncthreads();
  int acc = 0;
  for (int i = tid; i < T_LEN * BSZ; i += 256)
    if ((i & 3) != 0 && mask[i] != 0) acc = 1;
  if (acc) atomicOr(&s_any, 1);
  __syncthreads();
  const int mmode = s_any ? 0 : 1;   // 1 => int32 layout, 0 => byte layout
  const int wv = tid >> 6, lane = tid & 63;
  const int b = wv;
  int run = 0;
  for (int j0 = 0; j0 < T_LEN; j0 += 64) {
    const int j = j0 + lane;
    const int mval = mmode ? ((const int*)mask)[(size_t)j * BSZ + b]
                           : (int)mask[(size_t)j * BSZ + b];
    const int keep = (mval == 0) ? 1 : 0;
    int x = keep;
#pragma unroll
    for (int off = 1; off < 64; off <<= 1) {
      const int y = __shfl_up(x, off, 64);
      if (lane >= off) x += y;
    }
    pos[b * T_LEN + j] = keep ? (run + x - keep) : -1;
    run += __shfl(x, 63, 64);
  }
  if (lane == 0) nkeys[b] = run;
}

// ======== 256-row-tile, BK=32, 4-slot ring GEMM core (8-phase-style) ========
// 512 threads = 8 waves. Counted vmcnt: prefetch distance 3 K-tiles; the main
// loop NEVER drains vmcnt to 0. Raw s_barrier (no implicit drain). Per-K-tile:
// top {vmcnt(N); barrier} then PH phases of
// {ds_read frags | issue stage loads; barrier; lgkmcnt(0); setprio(1); 16 MFMA; setprio(0); barrier}.
// XOR-swizzle (involution, rule #21): physical 16B granule = logical ^ ((row>>1)&3),
// applied on BOTH the pre-swizzled global source and the ds_read address.

__device__ __forceinline__ bf16x8 ldfrag(const unsigned short* slot, int row, int quad) {
  return *(const bf16x8*)(slot + row * 32 + (((quad ^ (row >> 1)) & 3) * 8));
}

template<int C>
__device__ __forceinline__ void stage32(const unsigned short* gsrc,   // tile base (incl. kt*32)
                                        unsigned short* slot, int tid) {
#pragma unroll
  for (int c = 0; c < C; ++c) {
    const int g = c * 512 + tid;
    const int row = g >> 2;                        // 4 granules (64B) per row
    const int lc = (g ^ (row >> 1)) & 3;           // inverse-swizzled logical col16
    load_lds16(gsrc + (size_t)row * DMODEL + lc * 8,
               slot + c * 4096 + (tid >> 6) * 512);   // wave-uniform linear dest
  }
}

template<int N>
__device__ __forceinline__ void wait_vm() {
  if constexpr (N == 0)      asm volatile("s_waitcnt vmcnt(0)" ::: "memory");
  else if constexpr (N == 3) asm volatile("s_waitcnt vmcnt(3)" ::: "memory");
  else if constexpr (N == 4) asm volatile("s_waitcnt vmcnt(4)" ::: "memory");
  else if constexpr (N == 6) asm volatile("s_waitcnt vmcnt(6)" ::: "memory");
  else                       asm volatile("s_waitcnt vmcnt(8)" ::: "memory");
}

template<int MF, int NF, int BRA, int BRB>
__device__ __forceinline__ void gemm_ring(const unsigned short* __restrict__ Abase,
                                          const unsigned short* __restrict__ Bbase,
                                          unsigned short* As, unsigned short* Bs,
                                          f32x4 (&acc)[MF][NF],
                                          int tid, int mi, int quad, int wrow, int wcol) {
  constexpr int LA = BRA / 128, LB = BRB / 128;     // global_load_lds per thread per tile
  constexpr int SA = BRA * 32, SB = BRB * 32;       // slot size in shorts
  constexpr int PH = MF / 4;                        // phases per K-tile (16 MFMA each)
  constexpr int NKT = DMODEL / 32;                  // 32 K-tiles
  constexpr int INF = (LA + LB) * 2;                // 2 newer tiles in flight at the wait

  // prologue: stage tiles 0,1,2 into slots 0,1,2
#pragma unroll
  for (int p = 0; p < 3; ++p) {
    stage32<LA>(Abase + p * 32, As + p * SA, tid);
    stage32<LB>(Bbase + p * 32, Bs + p * SB, tid);
  }

  for (int kt = 0; kt < NKT; ++kt) {
    const unsigned short* Asl = As + (kt & 3) * SA;
    const unsigned short* Bsl = Bs + (kt & 3) * SB;
    unsigned short* Asw = As + ((kt + 3) & 3) * SA;
    unsigned short* Bsw = Bs + ((kt + 3) & 3) * SB;
    // counted wait: tile kt landed; 2 newer tiles stay in flight (tail drains 8->4->0)
    if (kt < NKT - 2)       wait_vm<INF>();
    else if (kt == NKT - 2) wait_vm<INF / 2>();
    else                    wait_vm<0>();
    __builtin_amdgcn_s_barrier();
    const bool pre = (kt + 3 < NKT);
    bf16x8 bfr[NF];
#pragma unroll
    for (int ph = 0; ph < PH; ++ph) {
      if (ph == 0) {
#pragma unroll
        for (int nf = 0; nf < NF; ++nf)
          bfr[nf] = ldfrag(Bsl, wcol + nf * 16 + mi, quad);   // B cached across phases
      }
      bf16x8 af[4];
#pragma unroll
      for (int m = 0; m < 4; ++m)
        af[m] = ldfrag(Asl, wrow + (ph * 4 + m) * 16 + mi, quad);
      if (pre) {
        if (ph == 0)      stage32<LA>(Abase + (kt + 3) * 32, Asw, tid);
        if (ph == PH - 1) stage32<LB>(Bbase + (kt + 3) * 32, Bsw, tid);
      }
      __builtin_amdgcn_s_barrier();
      asm volatile("s_waitcnt lgkmcnt(0)" ::: "memory");
      __builtin_amdgcn_sched_barrier(0);
      __builtin_amdgcn_s_setprio(1);
#pragma unroll
      for (int m = 0; m < 4; ++m)
#pragma unroll
        for (int nf = 0; nf < NF; ++nf)
          acc[ph * 4 + m][nf] = __builtin_amdgcn_mfma_f32_16x16x32_bf16(
              af[m], bfr[nf], acc[ph * 4 + m][nf], 0, 0, 0);
      __builtin_amdgcn_s_setprio(0);
      __builtin_amdgcn_s_barrier();
    }
  }
}

// ---- fused QKV projection; Q prescaled by L2E_SCALE; K/V^T compacted ----
// 256x256 tile, grid (3072/256, 8192/256) = (12, 32)
__global__ __launch_bounds__(512, 2) void gemm_qkv(const unsigned short* __restrict__ A,
                                                   const unsigned short* __restrict__ Wq,
                                                   const unsigned short* __restrict__ Wkv,
                                                   const int* __restrict__ pos,
                                                   unsigned short* __restrict__ outQ,
                                                   unsigned short* __restrict__ outK,
                                                   unsigned short* __restrict__ outVt) {
  __shared__ alignas(16) unsigned short As[4 * 256 * 32];   // 64 KB
  __shared__ alignas(16) unsigned short Bs[4 * 256 * 32];   // 64 KB
  const int tid  = threadIdx.x;
  const int lane = tid & 63;
  const int wv   = tid >> 6;
  const int mi   = lane & 15;
  const int quad = lane >> 4;
  const int wrow = (wv >> 2) * 128;   // 2 wave-rows
  const int wcol = (wv & 3) * 64;     // 4 wave-cols
  const int m0 = blockIdx.y * 256;
  const int n0 = blockIdx.x * 256;
  const unsigned short* Abase = A + (size_t)m0 * DMODEL;
  const unsigned short* Bbase = (n0 < DMODEL) ? (Wq + (size_t)n0 * DMODEL)
                                              : (Wkv + (size_t)(n0 - DMODEL) * DMODEL);
  f32x4 acc[8][4] = {};
  gemm_ring<8, 4, 256, 256>(Abase, Bbase, As, Bs, acc, tid, mi, quad, wrow, wcol);

  const int region = n0 >> 10;  // uniform per block (256 | 1024)
#pragma unroll
  for (int mf = 0; mf < 8; mf++) {
#pragma unroll
    for (int r = 0; r < 4; r++) {
      const int gm = m0 + wrow + mf * 16 + quad * 4 + r;
      const int i = gm >> 2, b = gm & 3;
      int p = i;
      if (region > 0) p = pos[b * T_LEN + i];
      if (region > 0 && p < 0) continue;   // masked key: drop
#pragma unroll
      for (int nf = 0; nf < 4; nf++) {
        const int gn = n0 + wcol + nf * 16 + mi;
        const int gnl = gn & (DMODEL - 1);
        const int hn = gnl >> 6, d = gnl & 63;
        const float v = acc[mf][nf][r];
        if (region == 0)
          outQ[(((size_t)b * NHEAD + hn) * T_LEN + i) * DHEAD + d] = f2bf(v * L2E_SCALE);
        else if (region == 1)
          outK[(((size_t)b * NHEAD + hn) * T_LEN + p) * DHEAD + d] = f2bf(v);
        else
          outVt[(((size_t)b * NHEAD + hn) * DHEAD + d) * T_LEN + p] = f2bf(v);
      }
    }
  }
}

// ---- output projection: AV(8192x1024) * wo^T -> bf16 AO ----
// 256x128 tile, grid (1024/128, 8192/256) = (8, 32) = exactly 1 block/CU
__global__ __launch_bounds__(512, 2) void gemm_out(const unsigned short* __restrict__ A,
                                                   const unsigned short* __restrict__ Bw,
                                                   unsigned short* __restrict__ outB) {
  __shared__ alignas(16) unsigned short As[4 * 256 * 32];   // 64 KB
  __shared__ alignas(16) unsigned short Bs[4 * 128 * 32];   // 32 KB
  const int tid  = threadIdx.x;
  const int lane = tid & 63;
  const int wv   = tid >> 6;
  const int mi   = lane & 15;
  const int quad = lane >> 4;
  const int wrow = (wv >> 1) * 64;    // 4 wave-rows
  const int wcol = (wv & 1) * 64;     // 2 wave-cols
  const int m0 = blockIdx.y * 256;
  const int n0 = blockIdx.x * 128;
  const unsigned short* Abase = A  + (size_t)m0 * DMODEL;
  const unsigned short* Bbase = Bw + (size_t)n0 * DMODEL;
  f32x4 acc[4][4] = {};
  gemm_ring<4, 4, 256, 128>(Abase, Bbase, As, Bs, acc, tid, mi, quad, wrow, wcol);

#pragma unroll
  for (int mf = 0; mf < 4; mf++)
#pragma unroll
    for (int nf = 0; nf < 4; nf++)
#pragma unroll
      for (int r = 0; r < 4; r++) {
        const int gm = m0 + wrow + mf * 16 + quad * 4 + r;
        const int gn = n0 + wcol + nf * 16 + mi;
        outB[(size_t)gm * DMODEL + gn] = f2bf(acc[mf][nf][r]);
      }
}

// ---- attention chunk: S^T = K·Q^T (fixed-max exp2), P·V accumulate ----
template<bool TAIL>
__device__ __forceinline__ void attn_chunk(int j0, int nk, int mi, int quad,
    const unsigned short* Ks, const unsigned short* Vts, unsigned short* PsW,
    const bf16x8 (&qb)[2][2], f32x4 (&oc)[2][4], float (&rs)[2]) {
  f32x4 sc[2][4] = {};
#pragma unroll
  for (int ct = 0; ct < 4; ct++) {
    const bf16x8 kf0 = *(const bf16x8*)(Ks + (ct * 16 + mi) * ROW + quad * 8);
    const bf16x8 kf1 = *(const bf16x8*)(Ks + (ct * 16 + mi) * ROW + 32 + quad * 8);
#pragma unroll
    for (int g = 0; g < 2; g++) {
      sc[g][ct] = __builtin_amdgcn_mfma_f32_16x16x32_bf16(kf0, qb[g][0], sc[g][ct], 0, 0, 0);
      sc[g][ct] = __builtin_amdgcn_mfma_f32_16x16x32_bf16(kf1, qb[g][1], sc[g][ct], 0, 0, 0);
    }
  }
#pragma unroll
  for (int g = 0; g < 2; g++)
#pragma unroll
    for (int ct = 0; ct < 4; ct++) {
#pragma unroll
      for (int r = 0; r < 4; r++) {
        float p = __builtin_amdgcn_exp2f(sc[g][ct][r]);
        if (TAIL && (j0 + ct * 16 + quad * 4 + r >= nk)) p = 0.f;
        rs[g] += p;
        sc[g][ct][r] = p;
      }
      union { float f; unsigned u; } c0, c1, c2, c3;
      c0.f = sc[g][ct][0]; c1.f = sc[g][ct][1]; c2.f = sc[g][ct][2]; c3.f = sc[g][ct][3];
      const unsigned pk0 = (c0.u >> 16) | (c1.u & 0xFFFF0000u);   // bf16 trunc pack
      const unsigned pk1 = (c2.u >> 16) | (c3.u & 0xFFFF0000u);
      *(uint2*)(PsW + (g * 16 + mi) * ROW + ct * 16 + quad * 4) = make_uint2(pk0, pk1);
    }
  bf16x8 pa0[2], pa1[2];
#pragma unroll
  for (int g = 0; g < 2; g++) {
    pa0[g] = *(const bf16x8*)(PsW + (g * 16 + mi) * ROW + quad * 8);
    pa1[g] = *(const bf16x8*)(PsW + (g * 16 + mi) * ROW + 32 + quad * 8);
  }
#pragma unroll
  for (int ct = 0; ct < 4; ct++) {
    const bf16x8 vf0 = *(const bf16x8*)(Vts + (ct * 16 + mi) * ROW + quad * 8);
    const bf16x8 vf1 = *(const bf16x8*)(Vts + (ct * 16 + mi) * ROW + 32 + quad * 8);
#pragma unroll
    for (int g = 0; g < 2; g++) {
      oc[g][ct] = __builtin_amdgcn_mfma_f32_16x16x32_bf16(pa0[g], vf0, oc[g][ct], 0, 0, 0);
      oc[g][ct] = __builtin_amdgcn_mfma_f32_16x16x32_bf16(pa1[g], vf1, oc[g][ct], 0, 0, 0);
    }
  }
}

// grid (T/128, B, NH), 256 thr = 4 waves x 32 q-rows (2 groups of 16)
__global__ __launch_bounds__(256, 4) void attn_mfma(const unsigned short* __restrict__ Qg,
                                                    const unsigned short* __restrict__ Kg,
                                                    const unsigned short* __restrict__ Vtg,
                                                    const int* __restrict__ nkeys,
                                                    unsigned short* __restrict__ av) {
  __shared__ alignas(16) unsigned short smem[18688];
  unsigned short* Ks  = smem;
  unsigned short* Vts = smem + 4608;
  unsigned short* Qs  = smem + 9216;
  float* Ls = (float*)(smem + 18432);

  const int tid  = threadIdx.x;
  const int lane = tid & 63;
  const int wv   = tid >> 6;
  const int mi   = lane & 15;
  const int quad = lane >> 4;
  const int i0 = blockIdx.x * 128;
  const int b  = blockIdx.y;
  const int n  = blockIdx.z;
  const size_t base = ((size_t)b * NHEAD + n) * T_LEN * DHEAD;
  const int nk = nkeys[b];

  for (int it = tid; it < 1024; it += 256) {
    const int r = it >> 3, c8 = (it & 7) * 8;
    *(uint4*)(Qs + r * ROW + c8) = *(const uint4*)(Qg + base + (size_t)(i0 + r) * DHEAD + c8);
  }
  __syncthreads();
  bf16x8 qb[2][2];
#pragma unroll
  for (int g = 0; g < 2; g++) {
    qb[g][0] = *(const bf16x8*)(Qs + (wv * 32 + g * 16 + mi) * ROW + quad * 8);
    qb[g][1] = *(const bf16x8*)(Qs + (wv * 32 + g * 16 + mi) * ROW + 32 + quad * 8);
  }

  f32x4 oc[2][4] = {};
  float rs[2] = {0.f, 0.f};
  unsigned short* PsW = Qs + wv * 2304;   // 32*ROW per wave (aliases Qs; safe after barrier)

  const int nmain = nk & ~63;
  for (int j0 = 0; j0 < nmain; j0 += 64) {
    for (int it = tid; it < 512; it += 256) {
      const int r = it >> 3, c8 = (it & 7) * 8;
      *(uint4*)(Ks  + r * ROW + c8) = *(const uint4*)(Kg  + base + (size_t)(j0 + r) * DHEAD + c8);
      *(uint4*)(Vts + r * ROW + c8) = *(const uint4*)(Vtg + base + (size_t)r * T_LEN + j0 + c8);
    }
    __syncthreads();
    attn_chunk<false>(j0, nk, mi, quad, Ks, Vts, PsW, qb, oc, rs);
    __syncthreads();
  }
  if (nmain < nk) {
    for (int it = tid; it < 512; it += 256) {
      const int r = it >> 3, c8 = (it & 7) * 8;
      *(uint4*)(Ks  + r * ROW + c8) = *(const uint4*)(Kg  + base + (size_t)(nmain + r) * DHEAD + c8);
      *(uint4*)(Vts + r * ROW + c8) = *(const uint4*)(Vtg + base + (size_t)r * T_LEN + nmain + c8);
    }
    __syncthreads();
    attn_chunk<true>(nmain, nk, mi, quad, Ks, Vts, PsW, qb, oc, rs);
  }

#pragma unroll
  for (int g = 0; g < 2; g++) {
    float t = rs[g];
    t += __shfl_xor(t, 16, 64);
    t += __shfl_xor(t, 32, 64);
    rs[g] = t;
  }
  if (quad == 0) { Ls[wv * 32 + mi] = rs[0]; Ls[wv * 32 + 16 + mi] = rs[1]; }
  __syncthreads();
  float linv[2][4];
#pragma unroll
  for (int g = 0; g < 2; g++)
#pragma unroll
    for (int r = 0; r < 4; r++) {
      const float l = Ls[wv * 32 + g * 16 + quad * 4 + r];
      linv[g][r] = (l > 0.f) ? (1.f / l) : 0.f;
    }
#pragma unroll
  for (int g = 0; g < 2; g++)
#pragma unroll
    for (int ct = 0; ct < 4; ct++)
#pragma unroll
      for (int r = 0; r < 4; r++) {
        const int q = i0 + wv * 32 + g * 16 + quad * 4 + r;
        const int d = ct * 16 + mi;
        av[((size_t)q * BSZ + b) * DMODEL + n * DHEAD + d] = f2bf(oc[g][ct][r] * linv[g][r]);
      }
}

// ---- out = LayerNorm(h + attn_out)*g + b  (ao bf16, float4 paths) ----
__global__ __launch_bounds__(256) void ln_kernel(const float* __restrict__ h,
                                                 const unsigned short* __restrict__ ao,
                                                 const float* __restrict__ g,
                                                 const float* __restrict__ bb,
                                                 float* __restrict__ out) {
  __shared__ float red[16];
  const int row = blockIdx.x;
  const int tid = threadIdx.x;
  const size_t base = (size_t)row * DMODEL;
  const int c = tid * 4;
  const float4 hv = *(const float4*)(h + base + c);
  const ushort4 a4 = *(const ushort4*)(ao + base + c);
  float x[4] = { hv.x + bf2f(a4.x), hv.y + bf2f(a4.y), hv.z + bf2f(a4.z), hv.w + bf2f(a4.w) };
  float s = 0.f, sq = 0.f;
#pragma unroll
  for (int k = 0; k < 4; k++) { s += x[k]; sq += x[k] * x[k]; }
#pragma unroll
  for (int off = 32; off; off >>= 1) { s += __shfl_xor(s, off, 64); sq += __shfl_xor(sq, off, 64); }
  const int wv = tid >> 6, lane = tid & 63;
  if (lane == 0) { red[wv] = s; red[8 + wv] = sq; }
  __syncthreads();
  if (tid == 0) {
    float ts = 0.f, tq = 0.f;
    for (int w = 0; w < 4; w++) { ts += red[w]; tq += red[8 + w]; }
    red[4] = ts; red[12] = tq;
  }
  __syncthreads();
  const float mu  = red[4] * (1.f / DMODEL);
  const float var = red[12] * (1.f / DMODEL) - mu * mu;
  const float inv = rsqrtf(var + 1e-5f);
  const float4 gv = *(const float4*)(g + c);
  const float4 bv = *(const float4*)(bb + c);
  float4 o;
  o.x = (x[0] - mu) * inv * gv.x + bv.x;
  o.y = (x[1] - mu) * inv * gv.y + bv.y;
  o.z = (x[2] - mu) * inv * gv.z + bv.z;
  o.w = (x[3] - mu) * inv * gv.w + bv.w;
  *(float4*)(out + base + c) = o;
}

extern "C" void kernel_launch(void* const* d_in, const int* in_sizes, int n_in,
                              void* d_out, int out_size, void* d_ws, size_t ws_size,
                              hipStream_t stream) {
  (void)in_sizes; (void)n_in; (void)out_size; (void)ws_size;
  const float* h           = (const float*)d_in[0];
  const unsigned char* msk = (const unsigned char*)d_in[1];
  const float* wq          = (const float*)d_in[2];
  const float* wkv         = (const float*)d_in[3];
  const float* wo          = (const float*)d_in[4];
  const float* lng         = (const float*)d_in[5];
  const float* lnb         = (const float*)d_in[6];
  float* out = (float*)d_out;

  const size_t E  = (size_t)T_LEN * BSZ * DMODEL;        // 8.39M
  const size_t WQ = (size_t)NHEAD * DHEAD * DMODEL;      // 1.05M
  char* ws = (char*)d_ws;
  int* nkeys            = (int*)ws;                       ws += 16;
  int* pos              = (int*)ws;                       ws += (size_t)BSZ * T_LEN * 4;
  unsigned short* h_bf  = (unsigned short*)ws;            ws += E * 2;
  unsigned short* wq_bf = (unsigned short*)ws;            ws += WQ * 2;
  unsigned short* wkv_bf= (unsigned short*)ws;            ws += 2 * WQ * 2;
  unsigned short* wo_bf = (unsigned short*)ws;            ws += WQ * 2;
  unsigned short* Qb    = (unsigned short*)ws;            ws += E * 2;
  unsigned short* Kb    = (unsigned short*)ws;            ws += E * 2;
  unsigned short* Vtb   = (unsigned short*)ws;            ws += E * 2;
  unsigned short* AV    = (unsigned short*)ws;            ws += E * 2;
  unsigned short* AO    = (unsigned short*)ws;

  cvt_prep<<<dim3(12289), dim3(256), 0, stream>>>(h, wq, wkv, wo, msk,
                                                  h_bf, wq_bf, wkv_bf, wo_bf, pos, nkeys);
  gemm_qkv<<<dim3(3 * DMODEL / 256, T_LEN * BSZ / 256), dim3(512), 0, stream>>>(
      h_bf, wq_bf, wkv_bf, pos, Qb, Kb, Vtb);
  attn_mfma<<<dim3(T_LEN / 128, BSZ, NHEAD), dim3(256), 0, stream>>>(Qb, Kb, Vtb, nkeys, AV);
  gemm_out<<<dim3(DMODEL / 128, T_LEN * BSZ / 256), dim3(512), 0, stream>>>(AV, wo_bf, AO);
  ln_kernel<<<dim3(T_LEN * BSZ), dim3(256), 0, stream>>>(h, AO, lng, lnb, out);
}

// Round 2
// 327.303 us; speedup vs baseline: 1.0039x; 1.0039x over previous
//
#include <hip/hip_runtime.h>

#define T_LEN 2048
#define BSZ 4
#define NHEAD 16
#define DHEAD 64
#define DMODEL 1024
#define SCALE 0.125f
#define L2E_SCALE (0.125f * 1.44269504f)   // SCALE*log2(e): folded into Q at projection
#define ROW 72   // padded LDS row stride in bf16 (attn kernel)

typedef __bf16 bf16x8 __attribute__((ext_vector_type(8)));
typedef float f32x4 __attribute__((ext_vector_type(4)));

__device__ __forceinline__ float bf2f(unsigned short u) {
  union { unsigned int i; float f; } v; v.i = ((unsigned int)u) << 16; return v.f;
}
__device__ __forceinline__ unsigned short f2bf(float f) {
  union { float f; unsigned int i; } v; v.f = f;
  unsigned int r = v.i + 0x7fffu + ((v.i >> 16) & 1u);   // RNE
  return (unsigned short)(r >> 16);
}

typedef __attribute__((address_space(1))) void* gptr_t;
typedef __attribute__((address_space(3))) void* lptr_t;

__device__ __forceinline__ void load_lds16(const void* g, void* l) {
  __builtin_amdgcn_global_load_lds((gptr_t)g, (lptr_t)l, 16, 0, 0);
}

// ---- fused fp32->bf16 conversion (blocks 0..12287) + mask prep (block 12288) ----
__global__ __launch_bounds__(256) void cvt_prep(const float* __restrict__ h,
                                                const float* __restrict__ wq,
                                                const float* __restrict__ wkv,
                                                const float* __restrict__ wo,
                                                const unsigned char* __restrict__ mask,
                                                unsigned short* __restrict__ h_bf,
                                                unsigned short* __restrict__ wq_bf,
                                                unsigned short* __restrict__ wkv_bf,
                                                unsigned short* __restrict__ wo_bf,
                                                int* __restrict__ pos,
                                                int* __restrict__ nkeys) {
  const int tid = threadIdx.x;
  if (blockIdx.x < 12288) {
    const size_t E4 = (size_t)T_LEN * BSZ * DMODEL / 4;
    const size_t W4 = (size_t)NHEAD * DHEAD * DMODEL / 4;
    const size_t g = (size_t)blockIdx.x * 256 + tid;
    const float* src; unsigned short* dst; size_t off;
    if (g < E4)                { src = h;   dst = h_bf;   off = g; }
    else if (g < E4 + W4)      { src = wq;  dst = wq_bf;  off = g - E4; }
    else if (g < E4 + 3 * W4)  { src = wkv; dst = wkv_bf; off = g - E4 - W4; }
    else                       { src = wo;  dst = wo_bf;  off = g - E4 - 3 * W4; }
    const float4 v = *(const float4*)(src + off * 4);
    ushort4 o;
    o.x = f2bf(v.x); o.y = f2bf(v.y); o.z = f2bf(v.z); o.w = f2bf(v.w);
    *(ushort4*)(dst + off * 4) = o;
    return;
  }
  __shared__ int s_any;
  if (tid == 0) s_any = 0;
  __syncthreads();
  int acc = 0;
  for (int i = tid; i < T_LEN * BSZ; i += 256)
    if ((i & 3) != 0 && mask[i] != 0) acc = 1;
  if (acc) atomicOr(&s_any, 1);
  __syncthreads();
  const int mmode = s_any ? 0 : 1;   // 1 => int32 layout, 0 => byte layout
  const int wv = tid >> 6, lane = tid & 63;
  const int b = wv;
  int run = 0;
  for (int j0 = 0; j0 < T_LEN; j0 += 64) {
    const int j = j0 + lane;
    const int mval = mmode ? ((const int*)mask)[(size_t)j * BSZ + b]
                           : (int)mask[(size_t)j * BSZ + b];
    const int keep = (mval == 0) ? 1 : 0;
    int x = keep;
#pragma unroll
    for (int off = 1; off < 64; off <<= 1) {
      const int y = __shfl_up(x, off, 64);
      if (lane >= off) x += y;
    }
    pos[b * T_LEN + j] = keep ? (run + x - keep) : -1;
    run += __shfl(x, 63, 64);
  }
  if (lane == 0) nkeys[b] = run;
}

// ======== 256-row-tile, BK=32, 4-slot ring GEMM core ========
// 512 threads = 8 waves. Counted vmcnt: prefetch distance 3 K-tiles; the main
// loop NEVER drains vmcnt to 0. Raw s_barrier (no implicit drain). Per-K-tile:
// top {vmcnt(N); barrier} then PH phases of
// {ds_read frags | issue stage loads; barrier; lgkmcnt(0); setprio(1); 16 MFMA; setprio(0); barrier}.
// XOR-swizzle (involution, rule #21): physical 16B granule = logical ^ ((row>>1)&3),
// applied on BOTH the pre-swizzled global source and the ds_read address.
// NOTE (round-1 post-mortem): PH=1 config (256x128 tile, acc[4][4]) measured ~2.5x
// better per-FLOP than PH=2 (256x256); use PH=1 for all GEMMs.

__device__ __forceinline__ bf16x8 ldfrag(const unsigned short* slot, int row, int quad) {
  return *(const bf16x8*)(slot + row * 32 + (((quad ^ (row >> 1)) & 3) * 8));
}

template<int C>
__device__ __forceinline__ void stage32(const unsigned short* gsrc,   // tile base (incl. kt*32)
                                        unsigned short* slot, int tid) {
#pragma unroll
  for (int c = 0; c < C; ++c) {
    const int g = c * 512 + tid;
    const int row = g >> 2;                        // 4 granules (64B) per row
    const int lc = (g ^ (row >> 1)) & 3;           // inverse-swizzled logical col16
    load_lds16(gsrc + (size_t)row * DMODEL + lc * 8,
               slot + c * 4096 + (tid >> 6) * 512);   // wave-uniform linear dest
  }
}

template<int N>
__device__ __forceinline__ void wait_vm() {
  if constexpr (N == 0)      asm volatile("s_waitcnt vmcnt(0)" ::: "memory");
  else if constexpr (N == 3) asm volatile("s_waitcnt vmcnt(3)" ::: "memory");
  else if constexpr (N == 4) asm volatile("s_waitcnt vmcnt(4)" ::: "memory");
  else if constexpr (N == 6) asm volatile("s_waitcnt vmcnt(6)" ::: "memory");
  else                       asm volatile("s_waitcnt vmcnt(8)" ::: "memory");
}

template<int MF, int NF, int BRA, int BRB>
__device__ __forceinline__ void gemm_ring(const unsigned short* __restrict__ Abase,
                                          const unsigned short* __restrict__ Bbase,
                                          unsigned short* As, unsigned short* Bs,
                                          f32x4 (&acc)[MF][NF],
                                          int tid, int mi, int quad, int wrow, int wcol) {
  constexpr int LA = BRA / 128, LB = BRB / 128;     // global_load_lds per thread per tile
  constexpr int SA = BRA * 32, SB = BRB * 32;       // slot size in shorts
  constexpr int PH = MF / 4;                        // phases per K-tile (16 MFMA each)
  constexpr int NKT = DMODEL / 32;                  // 32 K-tiles
  constexpr int INF = (LA + LB) * 2;                // 2 newer tiles in flight at the wait

  // prologue: stage tiles 0,1,2 into slots 0,1,2
#pragma unroll
  for (int p = 0; p < 3; ++p) {
    stage32<LA>(Abase + p * 32, As + p * SA, tid);
    stage32<LB>(Bbase + p * 32, Bs + p * SB, tid);
  }

  for (int kt = 0; kt < NKT; ++kt) {
    const unsigned short* Asl = As + (kt & 3) * SA;
    const unsigned short* Bsl = Bs + (kt & 3) * SB;
    unsigned short* Asw = As + ((kt + 3) & 3) * SA;
    unsigned short* Bsw = Bs + ((kt + 3) & 3) * SB;
    // counted wait: tile kt landed; 2 newer tiles stay in flight (tail drains INF->INF/2->0)
    if (kt < NKT - 2)       wait_vm<INF>();
    else if (kt == NKT - 2) wait_vm<INF / 2>();
    else                    wait_vm<0>();
    __builtin_amdgcn_s_barrier();
    const bool pre = (kt + 3 < NKT);
    bf16x8 bfr[NF];
#pragma unroll
    for (int ph = 0; ph < PH; ++ph) {
      if (ph == 0) {
#pragma unroll
        for (int nf = 0; nf < NF; ++nf)
          bfr[nf] = ldfrag(Bsl, wcol + nf * 16 + mi, quad);   // B cached across phases
      }
      bf16x8 af[4];
#pragma unroll
      for (int m = 0; m < 4; ++m)
        af[m] = ldfrag(Asl, wrow + (ph * 4 + m) * 16 + mi, quad);
      if (pre) {
        if (ph == 0)      stage32<LA>(Abase + (kt + 3) * 32, Asw, tid);
        if (ph == PH - 1) stage32<LB>(Bbase + (kt + 3) * 32, Bsw, tid);
      }
      __builtin_amdgcn_s_barrier();
      asm volatile("s_waitcnt lgkmcnt(0)" ::: "memory");
      __builtin_amdgcn_sched_barrier(0);
      __builtin_amdgcn_s_setprio(1);
#pragma unroll
      for (int m = 0; m < 4; ++m)
#pragma unroll
        for (int nf = 0; nf < NF; ++nf)
          acc[ph * 4 + m][nf] = __builtin_amdgcn_mfma_f32_16x16x32_bf16(
              af[m], bfr[nf], acc[ph * 4 + m][nf], 0, 0, 0);
      __builtin_amdgcn_s_setprio(0);
      __builtin_amdgcn_s_barrier();
    }
  }
}

// ---- fused QKV projection; Q prescaled by L2E_SCALE; K/V^T compacted ----
// 256x128 tile (PH=1 ring, same config as gemm_out), grid (3072/128, 8192/256)
// = (24, 32) = 768 blocks = exactly 3 full rounds of 256 CUs.
__global__ __launch_bounds__(512, 2) void gemm_qkv(const unsigned short* __restrict__ A,
                                                   const unsigned short* __restrict__ Wq,
                                                   const unsigned short* __restrict__ Wkv,
                                                   const int* __restrict__ pos,
                                                   unsigned short* __restrict__ outQ,
                                                   unsigned short* __restrict__ outK,
                                                   unsigned short* __restrict__ outVt) {
  __shared__ alignas(16) unsigned short As[4 * 256 * 32];   // 64 KB
  __shared__ alignas(16) unsigned short Bs[4 * 128 * 32];   // 32 KB
  const int tid  = threadIdx.x;
  const int lane = tid & 63;
  const int wv   = tid >> 6;
  const int mi   = lane & 15;
  const int quad = lane >> 4;
  const int wrow = (wv >> 1) * 64;    // 4 wave-rows
  const int wcol = (wv & 1) * 64;     // 2 wave-cols
  const int m0 = blockIdx.y * 256;
  const int n0 = blockIdx.x * 128;
  const unsigned short* Abase = A + (size_t)m0 * DMODEL;
  const unsigned short* Bbase = (n0 < DMODEL) ? (Wq + (size_t)n0 * DMODEL)
                                              : (Wkv + (size_t)(n0 - DMODEL) * DMODEL);
  f32x4 acc[4][4] = {};
  gemm_ring<4, 4, 256, 128>(Abase, Bbase, As, Bs, acc, tid, mi, quad, wrow, wcol);

  const int region = n0 >> 10;  // uniform per block (tiles are 128-wide, regions 1024-aligned)
#pragma unroll
  for (int mf = 0; mf < 4; mf++) {
#pragma unroll
    for (int r = 0; r < 4; r++) {
      const int gm = m0 + wrow + mf * 16 + quad * 4 + r;
      const int i = gm >> 2, b = gm & 3;
      int p = i;
      if (region > 0) p = pos[b * T_LEN + i];
      if (region > 0 && p < 0) continue;   // masked key: drop
#pragma unroll
      for (int nf = 0; nf < 4; nf++) {
        const int gn = n0 + wcol + nf * 16 + mi;
        const int gnl = gn & (DMODEL - 1);
        const int hn = gnl >> 6, d = gnl & 63;
        const float v = acc[mf][nf][r];
        if (region == 0)
          outQ[(((size_t)b * NHEAD + hn) * T_LEN + i) * DHEAD + d] = f2bf(v * L2E_SCALE);
        else if (region == 1)
          outK[(((size_t)b * NHEAD + hn) * T_LEN + p) * DHEAD + d] = f2bf(v);
        else
          outVt[(((size_t)b * NHEAD + hn) * DHEAD + d) * T_LEN + p] = f2bf(v);
      }
    }
  }
}

// ---- output projection: AV(8192x1024) * wo^T -> bf16 AO ----
// 256x128 tile, grid (1024/128, 8192/256) = (8, 32) = exactly 1 block/CU
__global__ __launch_bounds__(512, 2) void gemm_out(const unsigned short* __restrict__ A,
                                                   const unsigned short* __restrict__ Bw,
                                                   unsigned short* __restrict__ outB) {
  __shared__ alignas(16) unsigned short As[4 * 256 * 32];   // 64 KB
  __shared__ alignas(16) unsigned short Bs[4 * 128 * 32];   // 32 KB
  const int tid  = threadIdx.x;
  const int lane = tid & 63;
  const int wv   = tid >> 6;
  const int mi   = lane & 15;
  const int quad = lane >> 4;
  const int wrow = (wv >> 1) * 64;    // 4 wave-rows
  const int wcol = (wv & 1) * 64;     // 2 wave-cols
  const int m0 = blockIdx.y * 256;
  const int n0 = blockIdx.x * 128;
  const unsigned short* Abase = A  + (size_t)m0 * DMODEL;
  const unsigned short* Bbase = Bw + (size_t)n0 * DMODEL;
  f32x4 acc[4][4] = {};
  gemm_ring<4, 4, 256, 128>(Abase, Bbase, As, Bs, acc, tid, mi, quad, wrow, wcol);

#pragma unroll
  for (int mf = 0; mf < 4; mf++)
#pragma unroll
    for (int nf = 0; nf < 4; nf++)
#pragma unroll
      for (int r = 0; r < 4; r++) {
        const int gm = m0 + wrow + mf * 16 + quad * 4 + r;
        const int gn = n0 + wcol + nf * 16 + mi;
        outB[(size_t)gm * DMODEL + gn] = f2bf(acc[mf][nf][r]);
      }
}

// ---- attention chunk: S^T = K·Q^T (fixed-max exp2), P·V accumulate ----
template<bool TAIL>
__device__ __forceinline__ void attn_chunk(int j0, int nk, int mi, int quad,
    const unsigned short* Ks, const unsigned short* Vts, unsigned short* PsW,
    const bf16x8 (&qb)[2][2], f32x4 (&oc)[2][4], float (&rs)[2]) {
  f32x4 sc[2][4] = {};
#pragma unroll
  for (int ct = 0; ct < 4; ct++) {
    const bf16x8 kf0 = *(const bf16x8*)(Ks + (ct * 16 + mi) * ROW + quad * 8);
    const bf16x8 kf1 = *(const bf16x8*)(Ks + (ct * 16 + mi) * ROW + 32 + quad * 8);
#pragma unroll
    for (int g = 0; g < 2; g++) {
      sc[g][ct] = __builtin_amdgcn_mfma_f32_16x16x32_bf16(kf0, qb[g][0], sc[g][ct], 0, 0, 0);
      sc[g][ct] = __builtin_amdgcn_mfma_f32_16x16x32_bf16(kf1, qb[g][1], sc[g][ct], 0, 0, 0);
    }
  }
#pragma unroll
  for (int g = 0; g < 2; g++)
#pragma unroll
    for (int ct = 0; ct < 4; ct++) {
#pragma unroll
      for (int r = 0; r < 4; r++) {
        float p = __builtin_amdgcn_exp2f(sc[g][ct][r]);
        if (TAIL && (j0 + ct * 16 + quad * 4 + r >= nk)) p = 0.f;
        rs[g] += p;
        sc[g][ct][r] = p;
      }
      union { float f; unsigned u; } c0, c1, c2, c3;
      c0.f = sc[g][ct][0]; c1.f = sc[g][ct][1]; c2.f = sc[g][ct][2]; c3.f = sc[g][ct][3];
      const unsigned pk0 = (c0.u >> 16) | (c1.u & 0xFFFF0000u);   // bf16 trunc pack
      const unsigned pk1 = (c2.u >> 16) | (c3.u & 0xFFFF0000u);
      *(uint2*)(PsW + (g * 16 + mi) * ROW + ct * 16 + quad * 4) = make_uint2(pk0, pk1);
    }
  bf16x8 pa0[2], pa1[2];
#pragma unroll
  for (int g = 0; g < 2; g++) {
    pa0[g] = *(const bf16x8*)(PsW + (g * 16 + mi) * ROW + quad * 8);
    pa1[g] = *(const bf16x8*)(PsW + (g * 16 + mi) * ROW + 32 + quad * 8);
  }
#pragma unroll
  for (int ct = 0; ct < 4; ct++) {
    const bf16x8 vf0 = *(const bf16x8*)(Vts + (ct * 16 + mi) * ROW + quad * 8);
    const bf16x8 vf1 = *(const bf16x8*)(Vts + (ct * 16 + mi) * ROW + 32 + quad * 8);
#pragma unroll
    for (int g = 0; g < 2; g++) {
      oc[g][ct] = __builtin_amdgcn_mfma_f32_16x16x32_bf16(pa0[g], vf0, oc[g][ct], 0, 0, 0);
      oc[g][ct] = __builtin_amdgcn_mfma_f32_16x16x32_bf16(pa1[g], vf1, oc[g][ct], 0, 0, 0);
    }
  }
}

// grid (T/128, B, NH), 256 thr = 4 waves x 32 q-rows (2 groups of 16)
__global__ __launch_bounds__(256, 4) void attn_mfma(const unsigned short* __restrict__ Qg,
                                                    const unsigned short* __restrict__ Kg,
                                                    const unsigned short* __restrict__ Vtg,
                                                    const int* __restrict__ nkeys,
                                                    unsigned short* __restrict__ av) {
  __shared__ alignas(16) unsigned short smem[18688];
  unsigned short* Ks  = smem;
  unsigned short* Vts = smem + 4608;
  unsigned short* Qs  = smem + 9216;
  float* Ls = (float*)(smem + 18432);

  const int tid  = threadIdx.x;
  const int lane = tid & 63;
  const int wv   = tid >> 6;
  const int mi   = lane & 15;
  const int quad = lane >> 4;
  const int i0 = blockIdx.x * 128;
  const int b  = blockIdx.y;
  const int n  = blockIdx.z;
  const size_t base = ((size_t)b * NHEAD + n) * T_LEN * DHEAD;
  const int nk = nkeys[b];

  for (int it = tid; it < 1024; it += 256) {
    const int r = it >> 3, c8 = (it & 7) * 8;
    *(uint4*)(Qs + r * ROW + c8) = *(const uint4*)(Qg + base + (size_t)(i0 + r) * DHEAD + c8);
  }
  __syncthreads();
  bf16x8 qb[2][2];
#pragma unroll
  for (int g = 0; g < 2; g++) {
    qb[g][0] = *(const bf16x8*)(Qs + (wv * 32 + g * 16 + mi) * ROW + quad * 8);
    qb[g][1] = *(const bf16x8*)(Qs + (wv * 32 + g * 16 + mi) * ROW + 32 + quad * 8);
  }

  f32x4 oc[2][4] = {};
  float rs[2] = {0.f, 0.f};
  unsigned short* PsW = Qs + wv * 2304;   // 32*ROW per wave (aliases Qs; safe after barrier)

  const int nmain = nk & ~63;
  for (int j0 = 0; j0 < nmain; j0 += 64) {
    for (int it = tid; it < 512; it += 256) {
      const int r = it >> 3, c8 = (it & 7) * 8;
      *(uint4*)(Ks  + r * ROW + c8) = *(const uint4*)(Kg  + base + (size_t)(j0 + r) * DHEAD + c8);
      *(uint4*)(Vts + r * ROW + c8) = *(const uint4*)(Vtg + base + (size_t)r * T_LEN + j0 + c8);
    }
    __syncthreads();
    attn_chunk<false>(j0, nk, mi, quad, Ks, Vts, PsW, qb, oc, rs);
    __syncthreads();
  }
  if (nmain < nk) {
    for (int it = tid; it < 512; it += 256) {
      const int r = it >> 3, c8 = (it & 7) * 8;
      *(uint4*)(Ks  + r * ROW + c8) = *(const uint4*)(Kg  + base + (size_t)(nmain + r) * DHEAD + c8);
      *(uint4*)(Vts + r * ROW + c8) = *(const uint4*)(Vtg + base + (size_t)r * T_LEN + nmain + c8);
    }
    __syncthreads();
    attn_chunk<true>(nmain, nk, mi, quad, Ks, Vts, PsW, qb, oc, rs);
  }

#pragma unroll
  for (int g = 0; g < 2; g++) {
    float t = rs[g];
    t += __shfl_xor(t, 16, 64);
    t += __shfl_xor(t, 32, 64);
    rs[g] = t;
  }
  if (quad == 0) { Ls[wv * 32 + mi] = rs[0]; Ls[wv * 32 + 16 + mi] = rs[1]; }
  __syncthreads();
  float linv[2][4];
#pragma unroll
  for (int g = 0; g < 2; g++)
#pragma unroll
    for (int r = 0; r < 4; r++) {
      const float l = Ls[wv * 32 + g * 16 + quad * 4 + r];
      linv[g][r] = (l > 0.f) ? (1.f / l) : 0.f;
    }
#pragma unroll
  for (int g = 0; g < 2; g++)
#pragma unroll
    for (int ct = 0; ct < 4; ct++)
#pragma unroll
      for (int r = 0; r < 4; r++) {
        const int q = i0 + wv * 32 + g * 16 + quad * 4 + r;
        const int d = ct * 16 + mi;
        av[((size_t)q * BSZ + b) * DMODEL + n * DHEAD + d] = f2bf(oc[g][ct][r] * linv[g][r]);
      }
}

// ---- out = LayerNorm(h + attn_out)*g + b  (ao bf16, float4 paths) ----
__global__ __launch_bounds__(256) void ln_kernel(const float* __restrict__ h,
                                                 const unsigned short* __restrict__ ao,
                                                 const float* __restrict__ g,
                                                 const float* __restrict__ bb,
                                                 float* __restrict__ out) {
  __shared__ float red[16];
  const int row = blockIdx.x;
  const int tid = threadIdx.x;
  const size_t base = (size_t)row * DMODEL;
  const int c = tid * 4;
  const float4 hv = *(const float4*)(h + base + c);
  const ushort4 a4 = *(const ushort4*)(ao + base + c);
  float x[4] = { hv.x + bf2f(a4.x), hv.y + bf2f(a4.y), hv.z + bf2f(a4.z), hv.w + bf2f(a4.w) };
  float s = 0.f, sq = 0.f;
#pragma unroll
  for (int k = 0; k < 4; k++) { s += x[k]; sq += x[k] * x[k]; }
#pragma unroll
  for (int off = 32; off; off >>= 1) { s += __shfl_xor(s, off, 64); sq += __shfl_xor(sq, off, 64); }
  const int wv = tid >> 6, lane = tid & 63;
  if (lane == 0) { red[wv] = s; red[8 + wv] = sq; }
  __syncthreads();
  if (tid == 0) {
    float ts = 0.f, tq = 0.f;
    for (int w = 0; w < 4; w++) { ts += red[w]; tq += red[8 + w]; }
    red[4] = ts; red[12] = tq;
  }
  __syncthreads();
  const float mu  = red[4] * (1.f / DMODEL);
  const float var = red[12] * (1.f / DMODEL) - mu * mu;
  const float inv = rsqrtf(var + 1e-5f);
  const float4 gv = *(const float4*)(g + c);
  const float4 bv = *(const float4*)(bb + c);
  float4 o;
  o.x = (x[0] - mu) * inv * gv.x + bv.x;
  o.y = (x[1] - mu) * inv * gv.y + bv.y;
  o.z = (x[2] - mu) * inv * gv.z + bv.z;
  o.w = (x[3] - mu) * inv * gv.w + bv.w;
  *(float4*)(out + base + c) = o;
}

extern "C" void kernel_launch(void* const* d_in, const int* in_sizes, int n_in,
                              void* d_out, int out_size, void* d_ws, size_t ws_size,
                              hipStream_t stream) {
  (void)in_sizes; (void)n_in; (void)out_size; (void)ws_size;
  const float* h           = (const float*)d_in[0];
  const unsigned char* msk = (const unsigned char*)d_in[1];
  const float* wq          = (const float*)d_in[2];
  const float* wkv         = (const float*)d_in[3];
  const float* wo          = (const float*)d_in[4];
  const float* lng         = (const float*)d_in[5];
  const float* lnb         = (const float*)d_in[6];
  float* out = (float*)d_out;

  const size_t E  = (size_t)T_LEN * BSZ * DMODEL;        // 8.39M
  const size_t WQ = (size_t)NHEAD * DHEAD * DMODEL;      // 1.05M
  char* ws = (char*)d_ws;
  int* nkeys            = (int*)ws;                       ws += 16;
  int* pos              = (int*)ws;                       ws += (size_t)BSZ * T_LEN * 4;
  unsigned short* h_bf  = (unsigned short*)ws;            ws += E * 2;
  unsigned short* wq_bf = (unsigned short*)ws;            ws += WQ * 2;
  unsigned short* wkv_bf= (unsigned short*)ws;            ws += 2 * WQ * 2;
  unsigned short* wo_bf = (unsigned short*)ws;            ws += WQ * 2;
  unsigned short* Qb    = (unsigned short*)ws;            ws += E * 2;
  unsigned short* Kb    = (unsigned short*)ws;            ws += E * 2;
  unsigned short* Vtb   = (unsigned short*)ws;            ws += E * 2;
  unsigned short* AV    = (unsigned short*)ws;            ws += E * 2;
  unsigned short* AO    = (unsigned short*)ws;

  cvt_prep<<<dim3(12289), dim3(256), 0, stream>>>(h, wq, wkv, wo, msk,
                                                  h_bf, wq_bf, wkv_bf, wo_bf, pos, nkeys);
  gemm_qkv<<<dim3(3 * DMODEL / 128, T_LEN * BSZ / 256), dim3(512), 0, stream>>>(
      h_bf, wq_bf, wkv_bf, pos, Qb, Kb, Vtb);
  attn_mfma<<<dim3(T_LEN / 128, BSZ, NHEAD), dim3(256), 0, stream>>>(Qb, Kb, Vtb, nkeys, AV);
  gemm_out<<<dim3(DMODEL / 128, T_LEN * BSZ / 256), dim3(512), 0, stream>>>(AV, wo_bf, AO);
  ln_kernel<<<dim3(T_LEN * BSZ), dim3(256), 0, stream>>>(h, AO, lng, lnb, out);
}

// Round 3
// 323.285 us; speedup vs baseline: 1.0164x; 1.0124x over previous
//
#include <hip/hip_runtime.h>

#define T_LEN 2048
#define BSZ 4
#define NHEAD 16
#define DHEAD 64
#define DMODEL 1024
#define SCALE 0.125f
#define L2E_SCALE (0.125f * 1.44269504f)   // SCALE*log2(e): folded into Q at projection
#define ROW 72   // padded LDS row stride in bf16 (attn kernel)

typedef __bf16 bf16x8 __attribute__((ext_vector_type(8)));
typedef float f32x4 __attribute__((ext_vector_type(4)));

__device__ __forceinline__ float bf2f(unsigned short u) {
  union { unsigned int i; float f; } v; v.i = ((unsigned int)u) << 16; return v.f;
}
__device__ __forceinline__ unsigned short f2bf(float f) {
  union { float f; unsigned int i; } v; v.f = f;
  unsigned int r = v.i + 0x7fffu + ((v.i >> 16) & 1u);   // RNE
  return (unsigned short)(r >> 16);
}

typedef __attribute__((address_space(1))) void* gptr_t;
typedef __attribute__((address_space(3))) void* lptr_t;

__device__ __forceinline__ void load_lds16(const void* g, void* l) {
  __builtin_amdgcn_global_load_lds((gptr_t)g, (lptr_t)l, 16, 0, 0);
}

// ---- fused fp32->bf16 conversion (blocks 0..12287) + mask prep (block 12288) ----
__global__ __launch_bounds__(256) void cvt_prep(const float* __restrict__ h,
                                                const float* __restrict__ wq,
                                                const float* __restrict__ wkv,
                                                const float* __restrict__ wo,
                                                const unsigned char* __restrict__ mask,
                                                unsigned short* __restrict__ h_bf,
                                                unsigned short* __restrict__ wq_bf,
                                                unsigned short* __restrict__ wkv_bf,
                                                unsigned short* __restrict__ wo_bf,
                                                int* __restrict__ pos,
                                                int* __restrict__ nkeys) {
  const int tid = threadIdx.x;
  if (blockIdx.x < 12288) {
    const size_t E4 = (size_t)T_LEN * BSZ * DMODEL / 4;
    const size_t W4 = (size_t)NHEAD * DHEAD * DMODEL / 4;
    const size_t g = (size_t)blockIdx.x * 256 + tid;
    const float* src; unsigned short* dst; size_t off;
    if (g < E4)                { src = h;   dst = h_bf;   off = g; }
    else if (g < E4 + W4)      { src = wq;  dst = wq_bf;  off = g - E4; }
    else if (g < E4 + 3 * W4)  { src = wkv; dst = wkv_bf; off = g - E4 - W4; }
    else                       { src = wo;  dst = wo_bf;  off = g - E4 - 3 * W4; }
    const float4 v = *(const float4*)(src + off * 4);
    ushort4 o;
    o.x = f2bf(v.x); o.y = f2bf(v.y); o.z = f2bf(v.z); o.w = f2bf(v.w);
    *(ushort4*)(dst + off * 4) = o;
    return;
  }
  __shared__ int s_any;
  if (tid == 0) s_any = 0;
  __syncthreads();
  int acc = 0;
  for (int i = tid; i < T_LEN * BSZ; i += 256)
    if ((i & 3) != 0 && mask[i] != 0) acc = 1;
  if (acc) atomicOr(&s_any, 1);
  __syncthreads();
  const int mmode = s_any ? 0 : 1;   // 1 => int32 layout, 0 => byte layout
  const int wv = tid >> 6, lane = tid & 63;
  const int b = wv;
  int run = 0;
  for (int j0 = 0; j0 < T_LEN; j0 += 64) {
    const int j = j0 + lane;
    const int mval = mmode ? ((const int*)mask)[(size_t)j * BSZ + b]
                           : (int)mask[(size_t)j * BSZ + b];
    const int keep = (mval == 0) ? 1 : 0;
    int x = keep;
#pragma unroll
    for (int off = 1; off < 64; off <<= 1) {
      const int y = __shfl_up(x, off, 64);
      if (lane >= off) x += y;
    }
    pos[b * T_LEN + j] = keep ? (run + x - keep) : -1;
    run += __shfl(x, 63, 64);
  }
  if (lane == 0) nkeys[b] = run;
}

// ======== 128x128, BK=64, XOR-swizzled, DOUBLE-BUFFERED GEMM core ========
// (round-0 proven structure: qkv 98.6us/~522TF. Ring variants measured worse.)
#define GEMM64_DBUF(Aptr, Bptr)                                                        \
  const int tid  = threadIdx.x;                                                        \
  const int lane = tid & 63;                                                           \
  const int wv   = tid >> 6;                                                           \
  const int wr = (wv >> 1) * 64;                                                       \
  const int wc = (wv & 1) * 64;                                                        \
  const int mi   = lane & 15;                                                          \
  const int quad = lane >> 4;                                                          \
  f32x4 acc[4][4] = {};                                                                \
  int rowc[4], colc[4];                                                                \
  _Pragma("unroll")                                                                    \
  for (int c = 0; c < 4; c++) {                                                        \
    const int s = c * 256 + tid;                                                       \
    rowc[c] = s >> 3;                                                                  \
    colc[c] = ((s & 7) ^ (rowc[c] & 7)) * 8;                                           \
  }                                                                                    \
  const int swz = mi & 7;                                                              \
  _Pragma("unroll")                                                                    \
  for (int c = 0; c < 4; c++) {                                                        \
    load_lds16(Aptr + (size_t)rowc[c] * DMODEL + colc[c], As + c * 2048 + wv * 512);   \
    load_lds16(Bptr + (size_t)rowc[c] * DMODEL + colc[c], Bs + c * 2048 + wv * 512);   \
  }                                                                                    \
  for (int k0 = 0; k0 < DMODEL; k0 += 64) {                                            \
    const int cur = (k0 >> 6) & 1;                                                     \
    const unsigned short* Asr = As + cur * 8192;                                       \
    const unsigned short* Bsr = Bs + cur * 8192;                                       \
    unsigned short* Asw = As + (1 - cur) * 8192;                                       \
    unsigned short* Bsw = Bs + (1 - cur) * 8192;                                       \
    __syncthreads();                                                                   \
    if (k0 + 64 < DMODEL) {                                                            \
      _Pragma("unroll")                                                                \
      for (int c = 0; c < 4; c++) {                                                    \
        load_lds16(Aptr + (size_t)rowc[c] * DMODEL + k0 + 64 + colc[c], Asw + c * 2048 + wv * 512); \
        load_lds16(Bptr + (size_t)rowc[c] * DMODEL + k0 + 64 + colc[c], Bsw + c * 2048 + wv * 512); \
      }                                                                                \
    }                                                                                  \
    _Pragma("unroll")                                                                  \
    for (int kq = 0; kq < 2; kq++) {                                                   \
      const int cp = ((kq * 4 + quad) ^ swz) * 8;                                      \
      bf16x8 af[4], bfr[4];                                                            \
      _Pragma("unroll")                                                                \
      for (int rt = 0; rt < 4; rt++)                                                   \
        af[rt] = *(const bf16x8*)(Asr + (wr + rt * 16 + mi) * 64 + cp);                \
      _Pragma("unroll")                                                                \
      for (int ct = 0; ct < 4; ct++)                                                   \
        bfr[ct] = *(const bf16x8*)(Bsr + (wc + ct * 16 + mi) * 64 + cp);               \
      _Pragma("unroll")                                                                \
      for (int rt = 0; rt < 4; rt++)                                                   \
        _Pragma("unroll")                                                              \
        for (int ct = 0; ct < 4; ct++)                                                 \
          acc[rt][ct] = __builtin_amdgcn_mfma_f32_16x16x32_bf16(af[rt], bfr[ct], acc[rt][ct], 0, 0, 0); \
    }                                                                                  \
  }

// ---- fused QKV projection; Q prescaled by L2E_SCALE; K/V^T compacted ----
__global__ __launch_bounds__(256) void gemm_qkv(const unsigned short* __restrict__ A,
                                                const unsigned short* __restrict__ Wq,
                                                const unsigned short* __restrict__ Wkv,
                                                const int* __restrict__ pos,
                                                unsigned short* __restrict__ outQ,
                                                unsigned short* __restrict__ outK,
                                                unsigned short* __restrict__ outVt) {
  __shared__ alignas(16) unsigned short As[2 * 128 * 64];   // 32 KB
  __shared__ alignas(16) unsigned short Bs[2 * 128 * 64];   // 32 KB
  const int m0 = blockIdx.y * 128;
  const int n0 = blockIdx.x * 128;
  const unsigned short* Abase = A + (size_t)m0 * DMODEL;
  const unsigned short* Bbase = (n0 < DMODEL) ? (Wq + (size_t)n0 * DMODEL)
                                              : (Wkv + (size_t)(n0 - DMODEL) * DMODEL);
  GEMM64_DBUF(Abase, Bbase)

  const int region = n0 >> 10;  // uniform per block
#pragma unroll
  for (int rt = 0; rt < 4; rt++) {
#pragma unroll
    for (int r = 0; r < 4; r++) {
      const int gm = m0 + wr + rt * 16 + quad * 4 + r;
      const int i = gm >> 2, b = gm & 3;
      int p = i;
      if (region > 0) p = pos[b * T_LEN + i];
      if (region > 0 && p < 0) continue;   // masked key: drop
#pragma unroll
      for (int ct = 0; ct < 4; ct++) {
        const int gn = n0 + wc + ct * 16 + mi;
        const int gnl = gn & (DMODEL - 1);
        const int hn = gnl >> 6, d = gnl & 63;
        const float v = acc[rt][ct][r];
        if (region == 0)
          outQ[(((size_t)b * NHEAD + hn) * T_LEN + i) * DHEAD + d] = f2bf(v * L2E_SCALE);
        else if (region == 1)
          outK[(((size_t)b * NHEAD + hn) * T_LEN + p) * DHEAD + d] = f2bf(v);
        else
          outVt[(((size_t)b * NHEAD + hn) * DHEAD + d) * T_LEN + p] = f2bf(v);
      }
    }
  }
}

// ---- output projection: AV(8192x1024) * wo^T -> bf16 AO; 128x128, BK=64 dbuf ----
__global__ __launch_bounds__(256) void gemm_out(const unsigned short* __restrict__ A,
                                                const unsigned short* __restrict__ Bw,
                                                unsigned short* __restrict__ outB) {
  __shared__ alignas(16) unsigned short As[2 * 128 * 64];
  __shared__ alignas(16) unsigned short Bs[2 * 128 * 64];
  const int m0 = blockIdx.y * 128;
  const int n0 = blockIdx.x * 128;
  const unsigned short* Abase = A  + (size_t)m0 * DMODEL;
  const unsigned short* Bbase = Bw + (size_t)n0 * DMODEL;
  GEMM64_DBUF(Abase, Bbase)

#pragma unroll
  for (int rt = 0; rt < 4; rt++)
#pragma unroll
    for (int ct = 0; ct < 4; ct++)
#pragma unroll
      for (int r = 0; r < 4; r++) {
        const int gm = m0 + wr + rt * 16 + quad * 4 + r;
        const int gn = n0 + wc + ct * 16 + mi;
        outB[(size_t)gm * DMODEL + gn] = f2bf(acc[rt][ct][r]);
      }
}

// ---- attention chunk: S^T = K·Q^T (fixed-max exp2), P·V accumulate ----
template<bool TAIL>
__device__ __forceinline__ void attn_chunk(int j0, int nk, int mi, int quad,
    const unsigned short* Ks, const unsigned short* Vts, unsigned short* PsW,
    const bf16x8 (&qb)[2][2], f32x4 (&oc)[2][4], float (&rs)[2]) {
  f32x4 sc[2][4] = {};
#pragma unroll
  for (int ct = 0; ct < 4; ct++) {
    const bf16x8 kf0 = *(const bf16x8*)(Ks + (ct * 16 + mi) * ROW + quad * 8);
    const bf16x8 kf1 = *(const bf16x8*)(Ks + (ct * 16 + mi) * ROW + 32 + quad * 8);
#pragma unroll
    for (int g = 0; g < 2; g++) {
      sc[g][ct] = __builtin_amdgcn_mfma_f32_16x16x32_bf16(kf0, qb[g][0], sc[g][ct], 0, 0, 0);
      sc[g][ct] = __builtin_amdgcn_mfma_f32_16x16x32_bf16(kf1, qb[g][1], sc[g][ct], 0, 0, 0);
    }
  }
#pragma unroll
  for (int g = 0; g < 2; g++)
#pragma unroll
    for (int ct = 0; ct < 4; ct++) {
#pragma unroll
      for (int r = 0; r < 4; r++) {
        float p = __builtin_amdgcn_exp2f(sc[g][ct][r]);
        if (TAIL && (j0 + ct * 16 + quad * 4 + r >= nk)) p = 0.f;
        rs[g] += p;
        sc[g][ct][r] = p;
      }
      union { float f; unsigned u; } c0, c1, c2, c3;
      c0.f = sc[g][ct][0]; c1.f = sc[g][ct][1]; c2.f = sc[g][ct][2]; c3.f = sc[g][ct][3];
      const unsigned pk0 = (c0.u >> 16) | (c1.u & 0xFFFF0000u);   // bf16 trunc pack
      const unsigned pk1 = (c2.u >> 16) | (c3.u & 0xFFFF0000u);
      *(uint2*)(PsW + (g * 16 + mi) * ROW + ct * 16 + quad * 4) = make_uint2(pk0, pk1);
    }
  bf16x8 pa0[2], pa1[2];
#pragma unroll
  for (int g = 0; g < 2; g++) {
    pa0[g] = *(const bf16x8*)(PsW + (g * 16 + mi) * ROW + quad * 8);
    pa1[g] = *(const bf16x8*)(PsW + (g * 16 + mi) * ROW + 32 + quad * 8);
  }
#pragma unroll
  for (int ct = 0; ct < 4; ct++) {
    const bf16x8 vf0 = *(const bf16x8*)(Vts + (ct * 16 + mi) * ROW + quad * 8);
    const bf16x8 vf1 = *(const bf16x8*)(Vts + (ct * 16 + mi) * ROW + 32 + quad * 8);
#pragma unroll
    for (int g = 0; g < 2; g++) {
      oc[g][ct] = __builtin_amdgcn_mfma_f32_16x16x32_bf16(pa0[g], vf0, oc[g][ct], 0, 0, 0);
      oc[g][ct] = __builtin_amdgcn_mfma_f32_16x16x32_bf16(pa1[g], vf1, oc[g][ct], 0, 0, 0);
    }
  }
}

// grid (T/128, B, NH), 256 thr = 4 waves x 32 q-rows (2 groups of 16)
// T14 async-STAGE: issue next chunk's K/V global loads into regs BEFORE compute,
// ds_write them AFTER the read-barrier. HBM latency hides under MFMA+exp2.
// launch_bounds (256,3): +16 staging VGPRs need the 170-reg cap (4-block cap was 128).
__global__ __launch_bounds__(256, 3) void attn_mfma(const unsigned short* __restrict__ Qg,
                                                    const unsigned short* __restrict__ Kg,
                                                    const unsigned short* __restrict__ Vtg,
                                                    const int* __restrict__ nkeys,
                                                    unsigned short* __restrict__ av) {
  __shared__ alignas(16) unsigned short smem[18688];
  unsigned short* Ks  = smem;
  unsigned short* Vts = smem + 4608;
  unsigned short* Qs  = smem + 9216;
  float* Ls = (float*)(smem + 18432);

  const int tid  = threadIdx.x;
  const int lane = tid & 63;
  const int wv   = tid >> 6;
  const int mi   = lane & 15;
  const int quad = lane >> 4;
  const int i0 = blockIdx.x * 128;
  const int b  = blockIdx.y;
  const int n  = blockIdx.z;
  const size_t base = ((size_t)b * NHEAD + n) * T_LEN * DHEAD;
  const int nk = nkeys[b];

  for (int it = tid; it < 1024; it += 256) {
    const int r = it >> 3, c8 = (it & 7) * 8;
    *(uint4*)(Qs + r * ROW + c8) = *(const uint4*)(Qg + base + (size_t)(i0 + r) * DHEAD + c8);
  }
  __syncthreads();
  bf16x8 qb[2][2];
#pragma unroll
  for (int g = 0; g < 2; g++) {
    qb[g][0] = *(const bf16x8*)(Qs + (wv * 32 + g * 16 + mi) * ROW + quad * 8);
    qb[g][1] = *(const bf16x8*)(Qs + (wv * 32 + g * 16 + mi) * ROW + 32 + quad * 8);
  }

  f32x4 oc[2][4] = {};
  float rs[2] = {0.f, 0.f};
  unsigned short* PsW = Qs + wv * 2304;   // 32*ROW per wave (aliases Qs; safe after barrier)

  // per-thread staging geometry: each thread owns rows sr and sr+32, 16B col slice
  const int sr  = tid >> 3;
  const int sc8 = (tid & 7) * 8;
  uint4 kreg0, kreg1, vreg0, vreg1;

#define ATTN_ISSUE(J0)                                                                   \
  kreg0 = *(const uint4*)(Kg  + base + (size_t)((J0) + sr) * DHEAD + sc8);               \
  kreg1 = *(const uint4*)(Kg  + base + (size_t)((J0) + sr + 32) * DHEAD + sc8);          \
  vreg0 = *(const uint4*)(Vtg + base + (size_t)sr * T_LEN + (J0) + sc8);                 \
  vreg1 = *(const uint4*)(Vtg + base + (size_t)(sr + 32) * T_LEN + (J0) + sc8);

#define ATTN_COMMIT()                                                                    \
  *(uint4*)(Ks  + sr * ROW + sc8)        = kreg0;                                        \
  *(uint4*)(Ks  + (sr + 32) * ROW + sc8) = kreg1;                                        \
  *(uint4*)(Vts + sr * ROW + sc8)        = vreg0;                                        \
  *(uint4*)(Vts + (sr + 32) * ROW + sc8) = vreg1;

  const int nc = (nk + 63) >> 6;
  if (nc > 0) {
    ATTN_ISSUE(0)
    ATTN_COMMIT()
    __syncthreads();
    for (int c = 0; c < nc; ++c) {
      const int j0 = c * 64;
      if (c + 1 < nc) { ATTN_ISSUE(j0 + 64) }     // loads fly during compute
      if (c == nc - 1 && (nk & 63))
        attn_chunk<true>(j0, nk, mi, quad, Ks, Vts, PsW, qb, oc, rs);
      else
        attn_chunk<false>(j0, nk, mi, quad, Ks, Vts, PsW, qb, oc, rs);
      __syncthreads();                            // all waves done reading Ks/Vts
      if (c + 1 < nc) {
        ATTN_COMMIT()                             // vmcnt wait inserted by compiler
        __syncthreads();
      }
    }
  }
#undef ATTN_ISSUE
#undef ATTN_COMMIT

#pragma unroll
  for (int g = 0; g < 2; g++) {
    float t = rs[g];
    t += __shfl_xor(t, 16, 64);
    t += __shfl_xor(t, 32, 64);
    rs[g] = t;
  }
  if (quad == 0) { Ls[wv * 32 + mi] = rs[0]; Ls[wv * 32 + 16 + mi] = rs[1]; }
  __syncthreads();
  float linv[2][4];
#pragma unroll
  for (int g = 0; g < 2; g++)
#pragma unroll
    for (int r = 0; r < 4; r++) {
      const float l = Ls[wv * 32 + g * 16 + quad * 4 + r];
      linv[g][r] = (l > 0.f) ? (1.f / l) : 0.f;
    }
#pragma unroll
  for (int g = 0; g < 2; g++)
#pragma unroll
    for (int ct = 0; ct < 4; ct++)
#pragma unroll
      for (int r = 0; r < 4; r++) {
        const int q = i0 + wv * 32 + g * 16 + quad * 4 + r;
        const int d = ct * 16 + mi;
        av[((size_t)q * BSZ + b) * DMODEL + n * DHEAD + d] = f2bf(oc[g][ct][r] * linv[g][r]);
      }
}

// ---- out = LayerNorm(h + attn_out)*g + b  (ao bf16, float4 paths) ----
__global__ __launch_bounds__(256) void ln_kernel(const float* __restrict__ h,
                                                 const unsigned short* __restrict__ ao,
                                                 const float* __restrict__ g,
                                                 const float* __restrict__ bb,
                                                 float* __restrict__ out) {
  __shared__ float red[16];
  const int row = blockIdx.x;
  const int tid = threadIdx.x;
  const size_t base = (size_t)row * DMODEL;
  const int c = tid * 4;
  const float4 hv = *(const float4*)(h + base + c);
  const ushort4 a4 = *(const ushort4*)(ao + base + c);
  float x[4] = { hv.x + bf2f(a4.x), hv.y + bf2f(a4.y), hv.z + bf2f(a4.z), hv.w + bf2f(a4.w) };
  float s = 0.f, sq = 0.f;
#pragma unroll
  for (int k = 0; k < 4; k++) { s += x[k]; sq += x[k] * x[k]; }
#pragma unroll
  for (int off = 32; off; off >>= 1) { s += __shfl_xor(s, off, 64); sq += __shfl_xor(sq, off, 64); }
  const int wv = tid >> 6, lane = tid & 63;
  if (lane == 0) { red[wv] = s; red[8 + wv] = sq; }
  __syncthreads();
  if (tid == 0) {
    float ts = 0.f, tq = 0.f;
    for (int w = 0; w < 4; w++) { ts += red[w]; tq += red[8 + w]; }
    red[4] = ts; red[12] = tq;
  }
  __syncthreads();
  const float mu  = red[4] * (1.f / DMODEL);
  const float var = red[12] * (1.f / DMODEL) - mu * mu;
  const float inv = rsqrtf(var + 1e-5f);
  const float4 gv = *(const float4*)(g + c);
  const float4 bv = *(const float4*)(bb + c);
  float4 o;
  o.x = (x[0] - mu) * inv * gv.x + bv.x;
  o.y = (x[1] - mu) * inv * gv.y + bv.y;
  o.z = (x[2] - mu) * inv * gv.z + bv.z;
  o.w = (x[3] - mu) * inv * gv.w + bv.w;
  *(float4*)(out + base + c) = o;
}

extern "C" void kernel_launch(void* const* d_in, const int* in_sizes, int n_in,
                              void* d_out, int out_size, void* d_ws, size_t ws_size,
                              hipStream_t stream) {
  (void)in_sizes; (void)n_in; (void)out_size; (void)ws_size;
  const float* h           = (const float*)d_in[0];
  const unsigned char* msk = (const unsigned char*)d_in[1];
  const float* wq          = (const float*)d_in[2];
  const float* wkv         = (const float*)d_in[3];
  const float* wo          = (const float*)d_in[4];
  const float* lng         = (const float*)d_in[5];
  const float* lnb         = (const float*)d_in[6];
  float* out = (float*)d_out;

  const size_t E  = (size_t)T_LEN * BSZ * DMODEL;        // 8.39M
  const size_t WQ = (size_t)NHEAD * DHEAD * DMODEL;      // 1.05M
  char* ws = (char*)d_ws;
  int* nkeys            = (int*)ws;                       ws += 16;
  int* pos              = (int*)ws;                       ws += (size_t)BSZ * T_LEN * 4;
  unsigned short* h_bf  = (unsigned short*)ws;            ws += E * 2;
  unsigned short* wq_bf = (unsigned short*)ws;            ws += WQ * 2;
  unsigned short* wkv_bf= (unsigned short*)ws;            ws += 2 * WQ * 2;
  unsigned short* wo_bf = (unsigned short*)ws;            ws += WQ * 2;
  unsigned short* Qb    = (unsigned short*)ws;            ws += E * 2;
  unsigned short* Kb    = (unsigned short*)ws;            ws += E * 2;
  unsigned short* Vtb   = (unsigned short*)ws;            ws += E * 2;
  unsigned short* AV    = (unsigned short*)ws;            ws += E * 2;
  unsigned short* AO    = (unsigned short*)ws;

  const dim3 blk(256);
  cvt_prep<<<dim3(12289), blk, 0, stream>>>(h, wq, wkv, wo, msk,
                                            h_bf, wq_bf, wkv_bf, wo_bf, pos, nkeys);
  gemm_qkv<<<dim3(3 * DMODEL / 128, T_LEN * BSZ / 128), blk, 0, stream>>>(
      h_bf, wq_bf, wkv_bf, pos, Qb, Kb, Vtb);
  attn_mfma<<<dim3(T_LEN / 128, BSZ, NHEAD), blk, 0, stream>>>(Qb, Kb, Vtb, nkeys, AV);
  gemm_out<<<dim3(DMODEL / 128, T_LEN * BSZ / 128), blk, 0, stream>>>(AV, wo_bf, AO);
  ln_kernel<<<dim3(T_LEN * BSZ), blk, 0, stream>>>(h, AO, lng, lnb, out);
}

// Round 4
// 314.691 us; speedup vs baseline: 1.0441x; 1.0273x over previous
//
#include <hip/hip_runtime.h>

#define T_LEN 2048
#define BSZ 4
#define NHEAD 16
#define DHEAD 64
#define DMODEL 1024
#define SCALE 0.125f
#define L2E_SCALE (0.125f * 1.44269504f)   // SCALE*log2(e): folded into Q at projection

typedef __bf16 bf16x8 __attribute__((ext_vector_type(8)));
typedef float f32x4 __attribute__((ext_vector_type(4)));

__device__ __forceinline__ float bf2f(unsigned short u) {
  union { unsigned int i; float f; } v; v.i = ((unsigned int)u) << 16; return v.f;
}
__device__ __forceinline__ unsigned short f2bf(float f) {
  union { float f; unsigned int i; } v; v.f = f;
  unsigned int r = v.i + 0x7fffu + ((v.i >> 16) & 1u);   // RNE
  return (unsigned short)(r >> 16);
}

typedef __attribute__((address_space(1))) void* gptr_t;
typedef __attribute__((address_space(3))) void* lptr_t;

__device__ __forceinline__ void load_lds16(const void* g, void* l) {
  __builtin_amdgcn_global_load_lds((gptr_t)g, (lptr_t)l, 16, 0, 0);
}

// swizzled LDS addressing for attn buffers: stride 64 shorts (128B) per row,
// 16B granule XOR'd by (row&7). 64 lanes reading {rows=ct*16+mi, col granule quad}
// land <=2 lanes/bank (free) vs 8-way with the old +8 padding (7.5M conflict cyc).
__device__ __forceinline__ int swz16(int row, int g) {
  return row * 64 + ((g ^ (row & 7)) << 3);
}

// ---- fused fp32->bf16 conversion (blocks 0..12287) + mask prep (block 12288) ----
__global__ __launch_bounds__(256) void cvt_prep(const float* __restrict__ h,
                                                const float* __restrict__ wq,
                                                const float* __restrict__ wkv,
                                                const float* __restrict__ wo,
                                                const unsigned char* __restrict__ mask,
                                                unsigned short* __restrict__ h_bf,
                                                unsigned short* __restrict__ wq_bf,
                                                unsigned short* __restrict__ wkv_bf,
                                                unsigned short* __restrict__ wo_bf,
                                                int* __restrict__ pos,
                                                int* __restrict__ nkeys) {
  const int tid = threadIdx.x;
  if (blockIdx.x < 12288) {
    const size_t E4 = (size_t)T_LEN * BSZ * DMODEL / 4;
    const size_t W4 = (size_t)NHEAD * DHEAD * DMODEL / 4;
    const size_t g = (size_t)blockIdx.x * 256 + tid;
    const float* src; unsigned short* dst; size_t off;
    if (g < E4)                { src = h;   dst = h_bf;   off = g; }
    else if (g < E4 + W4)      { src = wq;  dst = wq_bf;  off = g - E4; }
    else if (g < E4 + 3 * W4)  { src = wkv; dst = wkv_bf; off = g - E4 - W4; }
    else                       { src = wo;  dst = wo_bf;  off = g - E4 - 3 * W4; }
    const float4 v = *(const float4*)(src + off * 4);
    ushort4 o;
    o.x = f2bf(v.x); o.y = f2bf(v.y); o.z = f2bf(v.z); o.w = f2bf(v.w);
    *(ushort4*)(dst + off * 4) = o;
    return;
  }
  __shared__ int s_any;
  if (tid == 0) s_any = 0;
  __syncthreads();
  int acc = 0;
  for (int i = tid; i < T_LEN * BSZ; i += 256)
    if ((i & 3) != 0 && mask[i] != 0) acc = 1;
  if (acc) atomicOr(&s_any, 1);
  __syncthreads();
  const int mmode = s_any ? 0 : 1;   // 1 => int32 layout, 0 => byte layout
  const int wv = tid >> 6, lane = tid & 63;
  const int b = wv;
  int run = 0;
  for (int j0 = 0; j0 < T_LEN; j0 += 64) {
    const int j = j0 + lane;
    const int mval = mmode ? ((const int*)mask)[(size_t)j * BSZ + b]
                           : (int)mask[(size_t)j * BSZ + b];
    const int keep = (mval == 0) ? 1 : 0;
    int x = keep;
#pragma unroll
    for (int off = 1; off < 64; off <<= 1) {
      const int y = __shfl_up(x, off, 64);
      if (lane >= off) x += y;
    }
    pos[b * T_LEN + j] = keep ? (run + x - keep) : -1;
    run += __shfl(x, 63, 64);
  }
  if (lane == 0) nkeys[b] = run;
}

// ======== 128x128, BK=64, XOR-swizzled, DOUBLE-BUFFERED GEMM core ========
// (round-0 proven structure: qkv ~99us/~522TF. Ring/8-phase variants measured worse.)
#define GEMM64_DBUF(Aptr, Bptr)                                                        \
  const int tid  = threadIdx.x;                                                        \
  const int lane = tid & 63;                                                           \
  const int wv   = tid >> 6;                                                           \
  const int wr = (wv >> 1) * 64;                                                       \
  const int wc = (wv & 1) * 64;                                                        \
  const int mi   = lane & 15;                                                          \
  const int quad = lane >> 4;                                                          \
  f32x4 acc[4][4] = {};                                                                \
  int rowc[4], colc[4];                                                                \
  _Pragma("unroll")                                                                    \
  for (int c = 0; c < 4; c++) {                                                        \
    const int s = c * 256 + tid;                                                       \
    rowc[c] = s >> 3;                                                                  \
    colc[c] = ((s & 7) ^ (rowc[c] & 7)) * 8;                                           \
  }                                                                                    \
  const int swz = mi & 7;                                                              \
  _Pragma("unroll")                                                                    \
  for (int c = 0; c < 4; c++) {                                                        \
    load_lds16(Aptr + (size_t)rowc[c] * DMODEL + colc[c], As + c * 2048 + wv * 512);   \
    load_lds16(Bptr + (size_t)rowc[c] * DMODEL + colc[c], Bs + c * 2048 + wv * 512);   \
  }                                                                                    \
  for (int k0 = 0; k0 < DMODEL; k0 += 64) {                                            \
    const int cur = (k0 >> 6) & 1;                                                     \
    const unsigned short* Asr = As + cur * 8192;                                       \
    const unsigned short* Bsr = Bs + cur * 8192;                                       \
    unsigned short* Asw = As + (1 - cur) * 8192;                                       \
    unsigned short* Bsw = Bs + (1 - cur) * 8192;                                       \
    __syncthreads();                                                                   \
    if (k0 + 64 < DMODEL) {                                                            \
      _Pragma("unroll")                                                                \
      for (int c = 0; c < 4; c++) {                                                    \
        load_lds16(Aptr + (size_t)rowc[c] * DMODEL + k0 + 64 + colc[c], Asw + c * 2048 + wv * 512); \
        load_lds16(Bptr + (size_t)rowc[c] * DMODEL + k0 + 64 + colc[c], Bsw + c * 2048 + wv * 512); \
      }                                                                                \
    }                                                                                  \
    _Pragma("unroll")                                                                  \
    for (int kq = 0; kq < 2; kq++) {                                                   \
      const int cp = ((kq * 4 + quad) ^ swz) * 8;                                      \
      bf16x8 af[4], bfr[4];                                                            \
      _Pragma("unroll")                                                                \
      for (int rt = 0; rt < 4; rt++)                                                   \
        af[rt] = *(const bf16x8*)(Asr + (wr + rt * 16 + mi) * 64 + cp);                \
      _Pragma("unroll")                                                                \
      for (int ct = 0; ct < 4; ct++)                                                   \
        bfr[ct] = *(const bf16x8*)(Bsr + (wc + ct * 16 + mi) * 64 + cp);               \
      _Pragma("unroll")                                                                \
      for (int rt = 0; rt < 4; rt++)                                                   \
        _Pragma("unroll")                                                              \
        for (int ct = 0; ct < 4; ct++)                                                 \
          acc[rt][ct] = __builtin_amdgcn_mfma_f32_16x16x32_bf16(af[rt], bfr[ct], acc[rt][ct], 0, 0, 0); \
    }                                                                                  \
  }

// ---- fused QKV projection; Q prescaled by L2E_SCALE; K/V^T compacted ----
__global__ __launch_bounds__(256) void gemm_qkv(const unsigned short* __restrict__ A,
                                                const unsigned short* __restrict__ Wq,
                                                const unsigned short* __restrict__ Wkv,
                                                const int* __restrict__ pos,
                                                unsigned short* __restrict__ outQ,
                                                unsigned short* __restrict__ outK,
                                                unsigned short* __restrict__ outVt) {
  __shared__ alignas(16) unsigned short As[2 * 128 * 64];   // 32 KB
  __shared__ alignas(16) unsigned short Bs[2 * 128 * 64];   // 32 KB
  const int m0 = blockIdx.y * 128;
  const int n0 = blockIdx.x * 128;
  const unsigned short* Abase = A + (size_t)m0 * DMODEL;
  const unsigned short* Bbase = (n0 < DMODEL) ? (Wq + (size_t)n0 * DMODEL)
                                              : (Wkv + (size_t)(n0 - DMODEL) * DMODEL);
  GEMM64_DBUF(Abase, Bbase)

  const int region = n0 >> 10;  // uniform per block
#pragma unroll
  for (int rt = 0; rt < 4; rt++) {
#pragma unroll
    for (int r = 0; r < 4; r++) {
      const int gm = m0 + wr + rt * 16 + quad * 4 + r;
      const int i = gm >> 2, b = gm & 3;
      int p = i;
      if (region > 0) p = pos[b * T_LEN + i];
      if (region > 0 && p < 0) continue;   // masked key: drop
#pragma unroll
      for (int ct = 0; ct < 4; ct++) {
        const int gn = n0 + wc + ct * 16 + mi;
        const int gnl = gn & (DMODEL - 1);
        const int hn = gnl >> 6, d = gnl & 63;
        const float v = acc[rt][ct][r];
        if (region == 0)
          outQ[(((size_t)b * NHEAD + hn) * T_LEN + i) * DHEAD + d] = f2bf(v * L2E_SCALE);
        else if (region == 1)
          outK[(((size_t)b * NHEAD + hn) * T_LEN + p) * DHEAD + d] = f2bf(v);
        else
          outVt[(((size_t)b * NHEAD + hn) * DHEAD + d) * T_LEN + p] = f2bf(v);
      }
    }
  }
}

// ---- output projection: AV(8192x1024) * wo^T -> bf16 AO; 128x128, BK=64 dbuf ----
__global__ __launch_bounds__(256) void gemm_out(const unsigned short* __restrict__ A,
                                                const unsigned short* __restrict__ Bw,
                                                unsigned short* __restrict__ outB) {
  __shared__ alignas(16) unsigned short As[2 * 128 * 64];
  __shared__ alignas(16) unsigned short Bs[2 * 128 * 64];
  const int m0 = blockIdx.y * 128;
  const int n0 = blockIdx.x * 128;
  const unsigned short* Abase = A  + (size_t)m0 * DMODEL;
  const unsigned short* Bbase = Bw + (size_t)n0 * DMODEL;
  GEMM64_DBUF(Abase, Bbase)

#pragma unroll
  for (int rt = 0; rt < 4; rt++)
#pragma unroll
    for (int ct = 0; ct < 4; ct++)
#pragma unroll
      for (int r = 0; r < 4; r++) {
        const int gm = m0 + wr + rt * 16 + quad * 4 + r;
        const int gn = n0 + wc + ct * 16 + mi;
        outB[(size_t)gm * DMODEL + gn] = f2bf(acc[rt][ct][r]);
      }
}

// ---- attention chunk: S^T = K·Q^T (fixed-max exp2), P·V accumulate ----
// All LDS accesses via swz16 layout (stride 64, granule XOR row&7): conflict-free.
template<bool TAIL>
__device__ __forceinline__ void attn_chunk(int j0, int nk, int mi, int quad,
    const unsigned short* Ks, const unsigned short* Vts, unsigned short* PsW,
    const bf16x8 (&qb)[2][2], f32x4 (&oc)[2][4], float (&rs)[2]) {
  f32x4 sc[2][4] = {};
#pragma unroll
  for (int ct = 0; ct < 4; ct++) {
    const bf16x8 kf0 = *(const bf16x8*)(Ks + swz16(ct * 16 + mi, quad));
    const bf16x8 kf1 = *(const bf16x8*)(Ks + swz16(ct * 16 + mi, 4 + quad));
#pragma unroll
    for (int g = 0; g < 2; g++) {
      sc[g][ct] = __builtin_amdgcn_mfma_f32_16x16x32_bf16(kf0, qb[g][0], sc[g][ct], 0, 0, 0);
      sc[g][ct] = __builtin_amdgcn_mfma_f32_16x16x32_bf16(kf1, qb[g][1], sc[g][ct], 0, 0, 0);
    }
  }
#pragma unroll
  for (int g = 0; g < 2; g++)
#pragma unroll
    for (int ct = 0; ct < 4; ct++) {
#pragma unroll
      for (int r = 0; r < 4; r++) {
        float p = __builtin_amdgcn_exp2f(sc[g][ct][r]);
        if (TAIL && (j0 + ct * 16 + quad * 4 + r >= nk)) p = 0.f;
        rs[g] += p;
        sc[g][ct][r] = p;
      }
      union { float f; unsigned u; } c0, c1, c2, c3;
      c0.f = sc[g][ct][0]; c1.f = sc[g][ct][1]; c2.f = sc[g][ct][2]; c3.f = sc[g][ct][3];
      const unsigned pk0 = (c0.u >> 16) | (c1.u & 0xFFFF0000u);   // bf16 trunc pack
      const unsigned pk1 = (c2.u >> 16) | (c3.u & 0xFFFF0000u);
      const int prow = g * 16 + mi;
      // col = ct*16 + quad*4 -> granule 2ct+(quad>>1), sub (quad&1)*4 shorts
      *(uint2*)(PsW + prow * 64 + (((2 * ct + (quad >> 1)) ^ (prow & 7)) << 3)
                + (quad & 1) * 4) = make_uint2(pk0, pk1);
    }
  bf16x8 pa0[2], pa1[2];
#pragma unroll
  for (int g = 0; g < 2; g++) {
    pa0[g] = *(const bf16x8*)(PsW + swz16(g * 16 + mi, quad));
    pa1[g] = *(const bf16x8*)(PsW + swz16(g * 16 + mi, 4 + quad));
  }
#pragma unroll
  for (int ct = 0; ct < 4; ct++) {
    const bf16x8 vf0 = *(const bf16x8*)(Vts + swz16(ct * 16 + mi, quad));
    const bf16x8 vf1 = *(const bf16x8*)(Vts + swz16(ct * 16 + mi, 4 + quad));
#pragma unroll
    for (int g = 0; g < 2; g++) {
      oc[g][ct] = __builtin_amdgcn_mfma_f32_16x16x32_bf16(pa0[g], vf0, oc[g][ct], 0, 0, 0);
      oc[g][ct] = __builtin_amdgcn_mfma_f32_16x16x32_bf16(pa1[g], vf1, oc[g][ct], 0, 0, 0);
    }
  }
}

// grid (T/128, B, NH), 256 thr = 4 waves x 32 q-rows (2 groups of 16)
__global__ __launch_bounds__(256, 4) void attn_mfma(const unsigned short* __restrict__ Qg,
                                                    const unsigned short* __restrict__ Kg,
                                                    const unsigned short* __restrict__ Vtg,
                                                    const int* __restrict__ nkeys,
                                                    unsigned short* __restrict__ av) {
  // Ks 64x64, Vts 64x64, Qs 128x64 (P regions alias Qs), Ls 128 floats
  __shared__ alignas(16) unsigned short smem[16640];
  unsigned short* Ks  = smem;            // 4096 shorts
  unsigned short* Vts = smem + 4096;     // 4096 shorts
  unsigned short* Qs  = smem + 8192;     // 8192 shorts
  float* Ls = (float*)(smem + 16384);

  const int tid  = threadIdx.x;
  const int lane = tid & 63;
  const int wv   = tid >> 6;
  const int mi   = lane & 15;
  const int quad = lane >> 4;
  const int i0 = blockIdx.x * 128;
  const int b  = blockIdx.y;
  const int n  = blockIdx.z;
  const size_t base = ((size_t)b * NHEAD + n) * T_LEN * DHEAD;
  const int nk = nkeys[b];

  for (int it = tid; it < 1024; it += 256) {
    const int r = it >> 3, g = it & 7;
    *(uint4*)(Qs + swz16(r, g)) = *(const uint4*)(Qg + base + (size_t)(i0 + r) * DHEAD + g * 8);
  }
  __syncthreads();
  bf16x8 qb[2][2];
#pragma unroll
  for (int g = 0; g < 2; g++) {
    qb[g][0] = *(const bf16x8*)(Qs + swz16(wv * 32 + g * 16 + mi, quad));
    qb[g][1] = *(const bf16x8*)(Qs + swz16(wv * 32 + g * 16 + mi, 4 + quad));
  }

  f32x4 oc[2][4] = {};
  float rs[2] = {0.f, 0.f};
  unsigned short* PsW = Qs + wv * 2048;   // 32 rows x 64 per wave (aliases Qs; safe after barrier)

  const int nmain = nk & ~63;
  for (int j0 = 0; j0 < nmain; j0 += 64) {
    for (int it = tid; it < 512; it += 256) {
      const int r = it >> 3, g = it & 7;
      *(uint4*)(Ks  + swz16(r, g)) = *(const uint4*)(Kg  + base + (size_t)(j0 + r) * DHEAD + g * 8);
      *(uint4*)(Vts + swz16(r, g)) = *(const uint4*)(Vtg + base + (size_t)r * T_LEN + j0 + g * 8);
    }
    __syncthreads();
    attn_chunk<false>(j0, nk, mi, quad, Ks, Vts, PsW, qb, oc, rs);
    __syncthreads();
  }
  if (nmain < nk) {
    for (int it = tid; it < 512; it += 256) {
      const int r = it >> 3, g = it & 7;
      *(uint4*)(Ks  + swz16(r, g)) = *(const uint4*)(Kg  + base + (size_t)(nmain + r) * DHEAD + g * 8);
      *(uint4*)(Vts + swz16(r, g)) = *(const uint4*)(Vtg + base + (size_t)r * T_LEN + nmain + g * 8);
    }
    __syncthreads();
    attn_chunk<true>(nmain, nk, mi, quad, Ks, Vts, PsW, qb, oc, rs);
  }

#pragma unroll
  for (int g = 0; g < 2; g++) {
    float t = rs[g];
    t += __shfl_xor(t, 16, 64);
    t += __shfl_xor(t, 32, 64);
    rs[g] = t;
  }
  if (quad == 0) { Ls[wv * 32 + mi] = rs[0]; Ls[wv * 32 + 16 + mi] = rs[1]; }
  __syncthreads();
  float linv[2][4];
#pragma unroll
  for (int g = 0; g < 2; g++)
#pragma unroll
    for (int r = 0; r < 4; r++) {
      const float l = Ls[wv * 32 + g * 16 + quad * 4 + r];
      linv[g][r] = (l > 0.f) ? (1.f / l) : 0.f;
    }
#pragma unroll
  for (int g = 0; g < 2; g++)
#pragma unroll
    for (int ct = 0; ct < 4; ct++)
#pragma unroll
      for (int r = 0; r < 4; r++) {
        const int q = i0 + wv * 32 + g * 16 + quad * 4 + r;
        const int d = ct * 16 + mi;
        av[((size_t)q * BSZ + b) * DMODEL + n * DHEAD + d] = f2bf(oc[g][ct][r] * linv[g][r]);
      }
}

// ---- out = LayerNorm(h + attn_out)*g + b  (ao bf16, float4 paths) ----
__global__ __launch_bounds__(256) void ln_kernel(const float* __restrict__ h,
                                                 const unsigned short* __restrict__ ao,
                                                 const float* __restrict__ g,
                                                 const float* __restrict__ bb,
                                                 float* __restrict__ out) {
  __shared__ float red[16];
  const int row = blockIdx.x;
  const int tid = threadIdx.x;
  const size_t base = (size_t)row * DMODEL;
  const int c = tid * 4;
  const float4 hv = *(const float4*)(h + base + c);
  const ushort4 a4 = *(const ushort4*)(ao + base + c);
  float x[4] = { hv.x + bf2f(a4.x), hv.y + bf2f(a4.y), hv.z + bf2f(a4.z), hv.w + bf2f(a4.w) };
  float s = 0.f, sq = 0.f;
#pragma unroll
  for (int k = 0; k < 4; k++) { s += x[k]; sq += x[k] * x[k]; }
#pragma unroll
  for (int off = 32; off; off >>= 1) { s += __shfl_xor(s, off, 64); sq += __shfl_xor(sq, off, 64); }
  const int wv = tid >> 6, lane = tid & 63;
  if (lane == 0) { red[wv] = s; red[8 + wv] = sq; }
  __syncthreads();
  if (tid == 0) {
    float ts = 0.f, tq = 0.f;
    for (int w = 0; w < 4; w++) { ts += red[w]; tq += red[8 + w]; }
    red[4] = ts; red[12] = tq;
  }
  __syncthreads();
  const float mu  = red[4] * (1.f / DMODEL);
  const float var = red[12] * (1.f / DMODEL) - mu * mu;
  const float inv = rsqrtf(var + 1e-5f);
  const float4 gv = *(const float4*)(g + c);
  const float4 bv = *(const float4*)(bb + c);
  float4 o;
  o.x = (x[0] - mu) * inv * gv.x + bv.x;
  o.y = (x[1] - mu) * inv * gv.y + bv.y;
  o.z = (x[2] - mu) * inv * gv.z + bv.z;
  o.w = (x[3] - mu) * inv * gv.w + bv.w;
  *(float4*)(out + base + c) = o;
}

extern "C" void kernel_launch(void* const* d_in, const int* in_sizes, int n_in,
                              void* d_out, int out_size, void* d_ws, size_t ws_size,
                              hipStream_t stream) {
  (void)in_sizes; (void)n_in; (void)out_size; (void)ws_size;
  const float* h           = (const float*)d_in[0];
  const unsigned char* msk = (const unsigned char*)d_in[1];
  const float* wq          = (const float*)d_in[2];
  const float* wkv         = (const float*)d_in[3];
  const float* wo          = (const float*)d_in[4];
  const float* lng         = (const float*)d_in[5];
  const float* lnb         = (const float*)d_in[6];
  float* out = (float*)d_out;

  const size_t E  = (size_t)T_LEN * BSZ * DMODEL;        // 8.39M
  const size_t WQ = (size_t)NHEAD * DHEAD * DMODEL;      // 1.05M
  char* ws = (char*)d_ws;
  int* nkeys            = (int*)ws;                       ws += 16;
  int* pos              = (int*)ws;                       ws += (size_t)BSZ * T_LEN * 4;
  unsigned short* h_bf  = (unsigned short*)ws;            ws += E * 2;
  unsigned short* wq_bf = (unsigned short*)ws;            ws += WQ * 2;
  unsigned short* wkv_bf= (unsigned short*)ws;            ws += 2 * WQ * 2;
  unsigned short* wo_bf = (unsigned short*)ws;            ws += WQ * 2;
  unsigned short* Qb    = (unsigned short*)ws;            ws += E * 2;
  unsigned short* Kb    = (unsigned short*)ws;            ws += E * 2;
  unsigned short* Vtb   = (unsigned short*)ws;            ws += E * 2;
  unsigned short* AV    = (unsigned short*)ws;            ws += E * 2;
  unsigned short* AO    = (unsigned short*)ws;

  const dim3 blk(256);
  cvt_prep<<<dim3(12289), blk, 0, stream>>>(h, wq, wkv, wo, msk,
                                            h_bf, wq_bf, wkv_bf, wo_bf, pos, nkeys);
  gemm_qkv<<<dim3(3 * DMODEL / 128, T_LEN * BSZ / 128), blk, 0, stream>>>(
      h_bf, wq_bf, wkv_bf, pos, Qb, Kb, Vtb);
  attn_mfma<<<dim3(T_LEN / 128, BSZ, NHEAD), blk, 0, stream>>>(Qb, Kb, Vtb, nkeys, AV);
  gemm_out<<<dim3(DMODEL / 128, T_LEN * BSZ / 128), blk, 0, stream>>>(AV, wo_bf, AO);
  ln_kernel<<<dim3(T_LEN * BSZ), blk, 0, stream>>>(h, AO, lng, lnb, out);
}

// Round 5
// 308.244 us; speedup vs baseline: 1.0660x; 1.0209x over previous
//
#include <hip/hip_runtime.h>

#define T_LEN 2048
#define BSZ 4
#define NHEAD 16
#define DHEAD 64
#define DMODEL 1024
#define SCALE 0.125f
#define L2E_SCALE (0.125f * 1.44269504f)   // SCALE*log2(e): folded into Q at projection

typedef __bf16 bf16x8 __attribute__((ext_vector_type(8)));
typedef float f32x4 __attribute__((ext_vector_type(4)));

__device__ __forceinline__ float bf2f(unsigned short u) {
  union { unsigned int i; float f; } v; v.i = ((unsigned int)u) << 16; return v.f;
}
__device__ __forceinline__ unsigned short f2bf(float f) {
  union { float f; unsigned int i; } v; v.f = f;
  unsigned int r = v.i + 0x7fffu + ((v.i >> 16) & 1u);   // RNE
  return (unsigned short)(r >> 16);
}

typedef __attribute__((address_space(1))) void* gptr_t;
typedef __attribute__((address_space(3))) void* lptr_t;

__device__ __forceinline__ void load_lds16(const void* g, void* l) {
  __builtin_amdgcn_global_load_lds((gptr_t)g, (lptr_t)l, 16, 0, 0);
}

// swizzled LDS addressing for attn buffers: stride 64 shorts (128B) per row,
// 16B granule XOR'd by (row&7). Reads conflict-free; staging writes are linear
// (global_load_lds) with the SAME involution applied to the global source.
__device__ __forceinline__ int swz16(int row, int g) {
  return row * 64 + ((g ^ (row & 7)) << 3);
}

// ---- fused fp32->bf16 conversion (blocks 0..12287) + mask prep (block 12288) ----
__global__ __launch_bounds__(256) void cvt_prep(const float* __restrict__ h,
                                                const float* __restrict__ wq,
                                                const float* __restrict__ wkv,
                                                const float* __restrict__ wo,
                                                const unsigned char* __restrict__ mask,
                                                unsigned short* __restrict__ h_bf,
                                                unsigned short* __restrict__ wq_bf,
                                                unsigned short* __restrict__ wkv_bf,
                                                unsigned short* __restrict__ wo_bf,
                                                int* __restrict__ pos,
                                                int* __restrict__ nkeys) {
  const int tid = threadIdx.x;
  if (blockIdx.x < 12288) {
    const size_t E4 = (size_t)T_LEN * BSZ * DMODEL / 4;
    const size_t W4 = (size_t)NHEAD * DHEAD * DMODEL / 4;
    const size_t g = (size_t)blockIdx.x * 256 + tid;
    const float* src; unsigned short* dst; size_t off;
    if (g < E4)                { src = h;   dst = h_bf;   off = g; }
    else if (g < E4 + W4)      { src = wq;  dst = wq_bf;  off = g - E4; }
    else if (g < E4 + 3 * W4)  { src = wkv; dst = wkv_bf; off = g - E4 - W4; }
    else                       { src = wo;  dst = wo_bf;  off = g - E4 - 3 * W4; }
    const float4 v = *(const float4*)(src + off * 4);
    ushort4 o;
    o.x = f2bf(v.x); o.y = f2bf(v.y); o.z = f2bf(v.z); o.w = f2bf(v.w);
    *(ushort4*)(dst + off * 4) = o;
    return;
  }
  __shared__ int s_any;
  if (tid == 0) s_any = 0;
  __syncthreads();
  int acc = 0;
  for (int i = tid; i < T_LEN * BSZ; i += 256)
    if ((i & 3) != 0 && mask[i] != 0) acc = 1;
  if (acc) atomicOr(&s_any, 1);
  __syncthreads();
  const int mmode = s_any ? 0 : 1;   // 1 => int32 layout, 0 => byte layout
  const int wv = tid >> 6, lane = tid & 63;
  const int b = wv;
  int run = 0;
  for (int j0 = 0; j0 < T_LEN; j0 += 64) {
    const int j = j0 + lane;
    const int mval = mmode ? ((const int*)mask)[(size_t)j * BSZ + b]
                           : (int)mask[(size_t)j * BSZ + b];
    const int keep = (mval == 0) ? 1 : 0;
    int x = keep;
#pragma unroll
    for (int off = 1; off < 64; off <<= 1) {
      const int y = __shfl_up(x, off, 64);
      if (lane >= off) x += y;
    }
    pos[b * T_LEN + j] = keep ? (run + x - keep) : -1;
    run += __shfl(x, 63, 64);
  }
  if (lane == 0) nkeys[b] = run;
}

// ======== 128x128, BK=64, XOR-swizzled, DOUBLE-BUFFERED GEMM core ========
// (round-0 proven structure: qkv ~99us/~522TF. Ring/8-phase variants measured worse.)
#define GEMM64_DBUF(Aptr, Bptr)                                                        \
  const int tid  = threadIdx.x;                                                        \
  const int lane = tid & 63;                                                           \
  const int wv   = tid >> 6;                                                           \
  const int wr = (wv >> 1) * 64;                                                       \
  const int wc = (wv & 1) * 64;                                                        \
  const int mi   = lane & 15;                                                          \
  const int quad = lane >> 4;                                                          \
  f32x4 acc[4][4] = {};                                                                \
  int rowc[4], colc[4];                                                                \
  _Pragma("unroll")                                                                    \
  for (int c = 0; c < 4; c++) {                                                        \
    const int s = c * 256 + tid;                                                       \
    rowc[c] = s >> 3;                                                                  \
    colc[c] = ((s & 7) ^ (rowc[c] & 7)) * 8;                                           \
  }                                                                                    \
  const int swz = mi & 7;                                                              \
  _Pragma("unroll")                                                                    \
  for (int c = 0; c < 4; c++) {                                                        \
    load_lds16(Aptr + (size_t)rowc[c] * DMODEL + colc[c], As + c * 2048 + wv * 512);   \
    load_lds16(Bptr + (size_t)rowc[c] * DMODEL + colc[c], Bs + c * 2048 + wv * 512);   \
  }                                                                                    \
  for (int k0 = 0; k0 < DMODEL; k0 += 64) {                                            \
    const int cur = (k0 >> 6) & 1;                                                     \
    const unsigned short* Asr = As + cur * 8192;                                       \
    const unsigned short* Bsr = Bs + cur * 8192;                                       \
    unsigned short* Asw = As + (1 - cur) * 8192;                                       \
    unsigned short* Bsw = Bs + (1 - cur) * 8192;                                       \
    __syncthreads();                                                                   \
    if (k0 + 64 < DMODEL) {                                                            \
      _Pragma("unroll")                                                                \
      for (int c = 0; c < 4; c++) {                                                    \
        load_lds16(Aptr + (size_t)rowc[c] * DMODEL + k0 + 64 + colc[c], Asw + c * 2048 + wv * 512); \
        load_lds16(Bptr + (size_t)rowc[c] * DMODEL + k0 + 64 + colc[c], Bsw + c * 2048 + wv * 512); \
      }                                                                                \
    }                                                                                  \
    _Pragma("unroll")                                                                  \
    for (int kq = 0; kq < 2; kq++) {                                                   \
      const int cp = ((kq * 4 + quad) ^ swz) * 8;                                      \
      bf16x8 af[4], bfr[4];                                                            \
      _Pragma("unroll")                                                                \
      for (int rt = 0; rt < 4; rt++)                                                   \
        af[rt] = *(const bf16x8*)(Asr + (wr + rt * 16 + mi) * 64 + cp);                \
      _Pragma("unroll")                                                                \
      for (int ct = 0; ct < 4; ct++)                                                   \
        bfr[ct] = *(const bf16x8*)(Bsr + (wc + ct * 16 + mi) * 64 + cp);               \
      _Pragma("unroll")                                                                \
      for (int rt = 0; rt < 4; rt++)                                                   \
        _Pragma("unroll")                                                              \
        for (int ct = 0; ct < 4; ct++)                                                 \
          acc[rt][ct] = __builtin_amdgcn_mfma_f32_16x16x32_bf16(af[rt], bfr[ct], acc[rt][ct], 0, 0, 0); \
    }                                                                                  \
  }

// ---- fused QKV projection; Q prescaled by L2E_SCALE; K/V^T compacted ----
__global__ __launch_bounds__(256) void gemm_qkv(const unsigned short* __restrict__ A,
                                                const unsigned short* __restrict__ Wq,
                                                const unsigned short* __restrict__ Wkv,
                                                const int* __restrict__ pos,
                                                unsigned short* __restrict__ outQ,
                                                unsigned short* __restrict__ outK,
                                                unsigned short* __restrict__ outVt) {
  __shared__ alignas(16) unsigned short As[2 * 128 * 64];   // 32 KB
  __shared__ alignas(16) unsigned short Bs[2 * 128 * 64];   // 32 KB
  const int m0 = blockIdx.y * 128;
  const int n0 = blockIdx.x * 128;
  const unsigned short* Abase = A + (size_t)m0 * DMODEL;
  const unsigned short* Bbase = (n0 < DMODEL) ? (Wq + (size_t)n0 * DMODEL)
                                              : (Wkv + (size_t)(n0 - DMODEL) * DMODEL);
  GEMM64_DBUF(Abase, Bbase)

  const int region = n0 >> 10;  // uniform per block
#pragma unroll
  for (int rt = 0; rt < 4; rt++) {
#pragma unroll
    for (int r = 0; r < 4; r++) {
      const int gm = m0 + wr + rt * 16 + quad * 4 + r;
      const int i = gm >> 2, b = gm & 3;
      int p = i;
      if (region > 0) p = pos[b * T_LEN + i];
      if (region > 0 && p < 0) continue;   // masked key: drop
#pragma unroll
      for (int ct = 0; ct < 4; ct++) {
        const int gn = n0 + wc + ct * 16 + mi;
        const int gnl = gn & (DMODEL - 1);
        const int hn = gnl >> 6, d = gnl & 63;
        const float v = acc[rt][ct][r];
        if (region == 0)
          outQ[(((size_t)b * NHEAD + hn) * T_LEN + i) * DHEAD + d] = f2bf(v * L2E_SCALE);
        else if (region == 1)
          outK[(((size_t)b * NHEAD + hn) * T_LEN + p) * DHEAD + d] = f2bf(v);
        else
          outVt[(((size_t)b * NHEAD + hn) * DHEAD + d) * T_LEN + p] = f2bf(v);
      }
    }
  }
}

// ---- output projection: AV(8192x1024) * wo^T -> bf16 AO; 128x128, BK=64 dbuf ----
__global__ __launch_bounds__(256) void gemm_out(const unsigned short* __restrict__ A,
                                                const unsigned short* __restrict__ Bw,
                                                unsigned short* __restrict__ outB) {
  __shared__ alignas(16) unsigned short As[2 * 128 * 64];
  __shared__ alignas(16) unsigned short Bs[2 * 128 * 64];
  const int m0 = blockIdx.y * 128;
  const int n0 = blockIdx.x * 128;
  const unsigned short* Abase = A  + (size_t)m0 * DMODEL;
  const unsigned short* Bbase = Bw + (size_t)n0 * DMODEL;
  GEMM64_DBUF(Abase, Bbase)

#pragma unroll
  for (int rt = 0; rt < 4; rt++)
#pragma unroll
    for (int ct = 0; ct < 4; ct++)
#pragma unroll
      for (int r = 0; r < 4; r++) {
        const int gm = m0 + wr + rt * 16 + quad * 4 + r;
        const int gn = n0 + wc + ct * 16 + mi;
        outB[(size_t)gm * DMODEL + gn] = f2bf(acc[rt][ct][r]);
      }
}

// ---- attention chunk: S^T = K·Q^T (fixed-max exp2), P·V accumulate ----
// All LDS reads via swz16 layout (stride 64, granule XOR row&7).
template<bool TAIL>
__device__ __forceinline__ void attn_chunk(int j0, int nk, int mi, int quad,
    const unsigned short* Ks, const unsigned short* Vts, unsigned short* PsW,
    const bf16x8 (&qb)[2][2], f32x4 (&oc)[2][4], float (&rs)[2]) {
  f32x4 sc[2][4] = {};
#pragma unroll
  for (int ct = 0; ct < 4; ct++) {
    const bf16x8 kf0 = *(const bf16x8*)(Ks + swz16(ct * 16 + mi, quad));
    const bf16x8 kf1 = *(const bf16x8*)(Ks + swz16(ct * 16 + mi, 4 + quad));
#pragma unroll
    for (int g = 0; g < 2; g++) {
      sc[g][ct] = __builtin_amdgcn_mfma_f32_16x16x32_bf16(kf0, qb[g][0], sc[g][ct], 0, 0, 0);
      sc[g][ct] = __builtin_amdgcn_mfma_f32_16x16x32_bf16(kf1, qb[g][1], sc[g][ct], 0, 0, 0);
    }
  }
#pragma unroll
  for (int g = 0; g < 2; g++)
#pragma unroll
    for (int ct = 0; ct < 4; ct++) {
#pragma unroll
      for (int r = 0; r < 4; r++) {
        float p = __builtin_amdgcn_exp2f(sc[g][ct][r]);
        if (TAIL && (j0 + ct * 16 + quad * 4 + r >= nk)) p = 0.f;
        rs[g] += p;
        sc[g][ct][r] = p;
      }
      union { float f; unsigned u; } c0, c1, c2, c3;
      c0.f = sc[g][ct][0]; c1.f = sc[g][ct][1]; c2.f = sc[g][ct][2]; c3.f = sc[g][ct][3];
      const unsigned pk0 = (c0.u >> 16) | (c1.u & 0xFFFF0000u);   // bf16 trunc pack
      const unsigned pk1 = (c2.u >> 16) | (c3.u & 0xFFFF0000u);
      const int prow = g * 16 + mi;
      // col = ct*16 + quad*4 -> granule 2ct+(quad>>1), sub (quad&1)*4 shorts
      *(uint2*)(PsW + prow * 64 + (((2 * ct + (quad >> 1)) ^ (prow & 7)) << 3)
                + (quad & 1) * 4) = make_uint2(pk0, pk1);
    }
  bf16x8 pa0[2], pa1[2];
#pragma unroll
  for (int g = 0; g < 2; g++) {
    pa0[g] = *(const bf16x8*)(PsW + swz16(g * 16 + mi, quad));
    pa1[g] = *(const bf16x8*)(PsW + swz16(g * 16 + mi, 4 + quad));
  }
#pragma unroll
  for (int ct = 0; ct < 4; ct++) {
    const bf16x8 vf0 = *(const bf16x8*)(Vts + swz16(ct * 16 + mi, quad));
    const bf16x8 vf1 = *(const bf16x8*)(Vts + swz16(ct * 16 + mi, 4 + quad));
#pragma unroll
    for (int g = 0; g < 2; g++) {
      oc[g][ct] = __builtin_amdgcn_mfma_f32_16x16x32_bf16(pa0[g], vf0, oc[g][ct], 0, 0, 0);
      oc[g][ct] = __builtin_amdgcn_mfma_f32_16x16x32_bf16(pa1[g], vf1, oc[g][ct], 0, 0, 0);
    }
  }
}

// async double-buffered K/V staging via global_load_lds: linear LDS dest
// (wave-uniform base + lane*16), inverse-swizzled global source (rule #21).
__device__ __forceinline__ void stage_kv(const unsigned short* __restrict__ Kg,
                                         const unsigned short* __restrict__ Vtg,
                                         size_t base, int j0s, unsigned short* kb,
                                         int tid, int wv) {
#pragma unroll
  for (int u = 0; u < 2; u++) {
    const int gi = u * 256 + tid;        // 16B granule index 0..511
    const int r = gi >> 3;               // row (K: key row / V: d row)
    const int gs = (gi ^ r) & 7;         // inverse-swizzled logical granule
    load_lds16(Kg + base + (size_t)(j0s + r) * DHEAD + gs * 8,
               kb + u * 2048 + wv * 512);
    load_lds16(Vtg + base + (size_t)r * T_LEN + j0s + gs * 8,
               kb + 4096 + u * 2048 + wv * 512);
  }
}

// grid (T/128, B, NH), 256 thr = 4 waves x 32 q-rows (2 groups of 16)
// K/V double-buffered via global_load_lds; ONE barrier per chunk (m97 schedule):
// loads for chunk c+1 issued right after the barrier, in flight across chunk c's
// compute, drained by the compiler's vmcnt(0) at the next barrier.
__global__ __launch_bounds__(256, 3) void attn_mfma(const unsigned short* __restrict__ Qg,
                                                    const unsigned short* __restrict__ Kg,
                                                    const unsigned short* __restrict__ Vtg,
                                                    const int* __restrict__ nkeys,
                                                    unsigned short* __restrict__ av) {
  // buf p: K at p*8192, V at p*8192+4096 (shorts); Qs/PsW at 16384; Ls at 24576
  __shared__ alignas(16) unsigned short smem[24832];
  unsigned short* Qs = smem + 16384;
  float* Ls = (float*)(smem + 24576);

  const int tid  = threadIdx.x;
  const int lane = tid & 63;
  const int wv   = tid >> 6;
  const int mi   = lane & 15;
  const int quad = lane >> 4;
  const int i0 = blockIdx.x * 128;
  const int b  = blockIdx.y;
  const int n  = blockIdx.z;
  const size_t base = ((size_t)b * NHEAD + n) * T_LEN * DHEAD;
  const int nk = nkeys[b];
  const int nc = (nk + 63) >> 6;

  for (int it = tid; it < 1024; it += 256) {
    const int r = it >> 3, g = it & 7;
    *(uint4*)(Qs + swz16(r, g)) = *(const uint4*)(Qg + base + (size_t)(i0 + r) * DHEAD + g * 8);
  }
  if (nc > 0) stage_kv(Kg, Vtg, base, 0, smem, tid, wv);
  __syncthreads();
  bf16x8 qb[2][2];
#pragma unroll
  for (int g = 0; g < 2; g++) {
    qb[g][0] = *(const bf16x8*)(Qs + swz16(wv * 32 + g * 16 + mi, quad));
    qb[g][1] = *(const bf16x8*)(Qs + swz16(wv * 32 + g * 16 + mi, 4 + quad));
  }

  f32x4 oc[2][4] = {};
  float rs[2] = {0.f, 0.f};
  unsigned short* PsW = Qs + wv * 2048;   // 32 rows x 64 per wave (own q-rows; disjoint)

  for (int c = 0; c < nc; ++c) {
    if (c + 1 < nc) stage_kv(Kg, Vtg, base, (c + 1) * 64, smem + ((c + 1) & 1) * 8192, tid, wv);
    const unsigned short* Kl = smem + (c & 1) * 8192;
    const unsigned short* Vl = Kl + 4096;
    if (c == nc - 1 && (nk & 63))
      attn_chunk<true>(c * 64, nk, mi, quad, Kl, Vl, PsW, qb, oc, rs);
    else
      attn_chunk<false>(c * 64, nk, mi, quad, Kl, Vl, PsW, qb, oc, rs);
    __syncthreads();   // drains staged loads (vmcnt0) + all waves done with Kl/Vl
  }

#pragma unroll
  for (int g = 0; g < 2; g++) {
    float t = rs[g];
    t += __shfl_xor(t, 16, 64);
    t += __shfl_xor(t, 32, 64);
    rs[g] = t;
  }
  if (quad == 0) { Ls[wv * 32 + mi] = rs[0]; Ls[wv * 32 + 16 + mi] = rs[1]; }
  __syncthreads();
  float linv[2][4];
#pragma unroll
  for (int g = 0; g < 2; g++)
#pragma unroll
    for (int r = 0; r < 4; r++) {
      const float l = Ls[wv * 32 + g * 16 + quad * 4 + r];
      linv[g][r] = (l > 0.f) ? (1.f / l) : 0.f;
    }
#pragma unroll
  for (int g = 0; g < 2; g++)
#pragma unroll
    for (int ct = 0; ct < 4; ct++)
#pragma unroll
      for (int r = 0; r < 4; r++) {
        const int q = i0 + wv * 32 + g * 16 + quad * 4 + r;
        const int d = ct * 16 + mi;
        av[((size_t)q * BSZ + b) * DMODEL + n * DHEAD + d] = f2bf(oc[g][ct][r] * linv[g][r]);
      }
}

// ---- out = LayerNorm(h + attn_out)*g + b : wave-per-row, zero barriers ----
// grid 2048 x 256 thr = 4 waves = 4 rows/block; lane holds 16 cols (4x float4).
__global__ __launch_bounds__(256) void ln_kernel(const float* __restrict__ h,
                                                 const unsigned short* __restrict__ ao,
                                                 const float* __restrict__ g,
                                                 const float* __restrict__ bb,
                                                 float* __restrict__ out) {
  const int tid = threadIdx.x, lane = tid & 63, wv = tid >> 6;
  const int row = blockIdx.x * 4 + wv;
  const size_t base = (size_t)row * DMODEL;
  float x[16];
  float s = 0.f, sq = 0.f;
#pragma unroll
  for (int k = 0; k < 4; k++) {
    const int c = lane * 4 + k * 256;
    const float4 hv = *(const float4*)(h + base + c);
    const ushort4 a4 = *(const ushort4*)(ao + base + c);
    x[k * 4 + 0] = hv.x + bf2f(a4.x);
    x[k * 4 + 1] = hv.y + bf2f(a4.y);
    x[k * 4 + 2] = hv.z + bf2f(a4.z);
    x[k * 4 + 3] = hv.w + bf2f(a4.w);
#pragma unroll
    for (int j = 0; j < 4; j++) { s += x[k * 4 + j]; sq += x[k * 4 + j] * x[k * 4 + j]; }
  }
#pragma unroll
  for (int off = 32; off; off >>= 1) { s += __shfl_xor(s, off, 64); sq += __shfl_xor(sq, off, 64); }
  const float mu  = s * (1.f / DMODEL);
  const float var = sq * (1.f / DMODEL) - mu * mu;
  const float inv = rsqrtf(var + 1e-5f);
#pragma unroll
  for (int k = 0; k < 4; k++) {
    const int c = lane * 4 + k * 256;
    const float4 gv = *(const float4*)(g + c);
    const float4 bv = *(const float4*)(bb + c);
    float4 o;
    o.x = (x[k * 4 + 0] - mu) * inv * gv.x + bv.x;
    o.y = (x[k * 4 + 1] - mu) * inv * gv.y + bv.y;
    o.z = (x[k * 4 + 2] - mu) * inv * gv.z + bv.z;
    o.w = (x[k * 4 + 3] - mu) * inv * gv.w + bv.w;
    *(float4*)(out + base + c) = o;
  }
}

extern "C" void kernel_launch(void* const* d_in, const int* in_sizes, int n_in,
                              void* d_out, int out_size, void* d_ws, size_t ws_size,
                              hipStream_t stream) {
  (void)in_sizes; (void)n_in; (void)out_size; (void)ws_size;
  const float* h           = (const float*)d_in[0];
  const unsigned char* msk = (const unsigned char*)d_in[1];
  const float* wq          = (const float*)d_in[2];
  const float* wkv         = (const float*)d_in[3];
  const float* wo          = (const float*)d_in[4];
  const float* lng         = (const float*)d_in[5];
  const float* lnb         = (const float*)d_in[6];
  float* out = (float*)d_out;

  const size_t E  = (size_t)T_LEN * BSZ * DMODEL;        // 8.39M
  const size_t WQ = (size_t)NHEAD * DHEAD * DMODEL;      // 1.05M
  char* ws = (char*)d_ws;
  int* nkeys            = (int*)ws;                       ws += 16;
  int* pos              = (int*)ws;                       ws += (size_t)BSZ * T_LEN * 4;
  unsigned short* h_bf  = (unsigned short*)ws;            ws += E * 2;
  unsigned short* wq_bf = (unsigned short*)ws;            ws += WQ * 2;
  unsigned short* wkv_bf= (unsigned short*)ws;            ws += 2 * WQ * 2;
  unsigned short* wo_bf = (unsigned short*)ws;            ws += WQ * 2;
  unsigned short* Qb    = (unsigned short*)ws;            ws += E * 2;
  unsigned short* Kb    = (unsigned short*)ws;            ws += E * 2;
  unsigned short* Vtb   = (unsigned short*)ws;            ws += E * 2;
  unsigned short* AV    = (unsigned short*)ws;            ws += E * 2;
  unsigned short* AO    = (unsigned short*)ws;

  const dim3 blk(256);
  cvt_prep<<<dim3(12289), blk, 0, stream>>>(h, wq, wkv, wo, msk,
                                            h_bf, wq_bf, wkv_bf, wo_bf, pos, nkeys);
  gemm_qkv<<<dim3(3 * DMODEL / 128, T_LEN * BSZ / 128), blk, 0, stream>>>(
      h_bf, wq_bf, wkv_bf, pos, Qb, Kb, Vtb);
  attn_mfma<<<dim3(T_LEN / 128, BSZ, NHEAD), blk, 0, stream>>>(Qb, Kb, Vtb, nkeys, AV);
  gemm_out<<<dim3(DMODEL / 128, T_LEN * BSZ / 128), blk, 0, stream>>>(AV, wo_bf, AO);
  ln_kernel<<<dim3(T_LEN * BSZ / 4), blk, 0, stream>>>(h, AO, lng, lnb, out);
}

// Round 6
// 304.253 us; speedup vs baseline: 1.0800x; 1.0131x over previous
//
#include <hip/hip_runtime.h>

#define T_LEN 2048
#define BSZ 4
#define NHEAD 16
#define DHEAD 64
#define DMODEL 1024
#define SCALE 0.125f
#define L2E_SCALE (0.125f * 1.44269504f)   // SCALE*log2(e): folded into Q at projection

typedef __bf16 bf16x8 __attribute__((ext_vector_type(8)));
typedef float f32x4 __attribute__((ext_vector_type(4)));

__device__ __forceinline__ float bf2f(unsigned short u) {
  union { unsigned int i; float f; } v; v.i = ((unsigned int)u) << 16; return v.f;
}
__device__ __forceinline__ unsigned short f2bf(float f) {
  union { float f; unsigned int i; } v; v.f = f;
  unsigned int r = v.i + 0x7fffu + ((v.i >> 16) & 1u);   // RNE
  return (unsigned short)(r >> 16);
}

typedef __attribute__((address_space(1))) void* gptr_t;
typedef __attribute__((address_space(3))) void* lptr_t;

__device__ __forceinline__ void load_lds16(const void* g, void* l) {
  __builtin_amdgcn_global_load_lds((gptr_t)g, (lptr_t)l, 16, 0, 0);
}

// swizzled LDS addressing for attn buffers: stride 64 shorts (128B) per row,
// 16B granule XOR'd by (row&7). Reads conflict-free; staging writes are linear
// (global_load_lds) with the SAME involution applied to the global source.
__device__ __forceinline__ int swz16(int row, int g) {
  return row * 64 + ((g ^ (row & 7)) << 3);
}

// ---- fused fp32->bf16 conversion (blocks 0..12287) + mask prep (block 12288) ----
__global__ __launch_bounds__(256) void cvt_prep(const float* __restrict__ h,
                                                const float* __restrict__ wq,
                                                const float* __restrict__ wkv,
                                                const float* __restrict__ wo,
                                                const unsigned char* __restrict__ mask,
                                                unsigned short* __restrict__ h_bf,
                                                unsigned short* __restrict__ wq_bf,
                                                unsigned short* __restrict__ wkv_bf,
                                                unsigned short* __restrict__ wo_bf,
                                                int* __restrict__ pos,
                                                int* __restrict__ nkeys) {
  const int tid = threadIdx.x;
  if (blockIdx.x < 12288) {
    const size_t E4 = (size_t)T_LEN * BSZ * DMODEL / 4;
    const size_t W4 = (size_t)NHEAD * DHEAD * DMODEL / 4;
    const size_t g = (size_t)blockIdx.x * 256 + tid;
    const float* src; unsigned short* dst; size_t off;
    if (g < E4)                { src = h;   dst = h_bf;   off = g; }
    else if (g < E4 + W4)      { src = wq;  dst = wq_bf;  off = g - E4; }
    else if (g < E4 + 3 * W4)  { src = wkv; dst = wkv_bf; off = g - E4 - W4; }
    else                       { src = wo;  dst = wo_bf;  off = g - E4 - 3 * W4; }
    const float4 v = *(const float4*)(src + off * 4);
    ushort4 o;
    o.x = f2bf(v.x); o.y = f2bf(v.y); o.z = f2bf(v.z); o.w = f2bf(v.w);
    *(ushort4*)(dst + off * 4) = o;
    return;
  }
  __shared__ int s_any;
  if (tid == 0) s_any = 0;
  __syncthreads();
  int acc = 0;
  for (int i = tid; i < T_LEN * BSZ; i += 256)
    if ((i & 3) != 0 && mask[i] != 0) acc = 1;
  if (acc) atomicOr(&s_any, 1);
  __syncthreads();
  const int mmode = s_any ? 0 : 1;   // 1 => int32 layout, 0 => byte layout
  const int wv = tid >> 6, lane = tid & 63;
  const int b = wv;
  int run = 0;
  for (int j0 = 0; j0 < T_LEN; j0 += 64) {
    const int j = j0 + lane;
    const int mval = mmode ? ((const int*)mask)[(size_t)j * BSZ + b]
                           : (int)mask[(size_t)j * BSZ + b];
    const int keep = (mval == 0) ? 1 : 0;
    int x = keep;
#pragma unroll
    for (int off = 1; off < 64; off <<= 1) {
      const int y = __shfl_up(x, off, 64);
      if (lane >= off) x += y;
    }
    pos[b * T_LEN + j] = keep ? (run + x - keep) : -1;
    run += __shfl(x, 63, 64);
  }
  if (lane == 0) nkeys[b] = run;
}

// ======== 128x128, BK=64, XOR-swizzled, DOUBLE-BUFFERED GEMM core ========
// (round-0 proven structure: qkv ~99us/~522TF. Ring/8-phase variants measured worse.)
#define GEMM64_DBUF(Aptr, Bptr)                                                        \
  const int tid  = threadIdx.x;                                                        \
  const int lane = tid & 63;                                                           \
  const int wv   = tid >> 6;                                                           \
  const int wr = (wv >> 1) * 64;                                                       \
  const int wc = (wv & 1) * 64;                                                        \
  const int mi   = lane & 15;                                                          \
  const int quad = lane >> 4;                                                          \
  f32x4 acc[4][4] = {};                                                                \
  int rowc[4], colc[4];                                                                \
  _Pragma("unroll")                                                                    \
  for (int c = 0; c < 4; c++) {                                                        \
    const int s = c * 256 + tid;                                                       \
    rowc[c] = s >> 3;                                                                  \
    colc[c] = ((s & 7) ^ (rowc[c] & 7)) * 8;                                           \
  }                                                                                    \
  const int swz = mi & 7;                                                              \
  _Pragma("unroll")                                                                    \
  for (int c = 0; c < 4; c++) {                                                        \
    load_lds16(Aptr + (size_t)rowc[c] * DMODEL + colc[c], As + c * 2048 + wv * 512);   \
    load_lds16(Bptr + (size_t)rowc[c] * DMODEL + colc[c], Bs + c * 2048 + wv * 512);   \
  }                                                                                    \
  for (int k0 = 0; k0 < DMODEL; k0 += 64) {                                            \
    const int cur = (k0 >> 6) & 1;                                                     \
    const unsigned short* Asr = As + cur * 8192;                                       \
    const unsigned short* Bsr = Bs + cur * 8192;                                       \
    unsigned short* Asw = As + (1 - cur) * 8192;                                       \
    unsigned short* Bsw = Bs + (1 - cur) * 8192;                                       \
    __syncthreads();                                                                   \
    if (k0 + 64 < DMODEL) {                                                            \
      _Pragma("unroll")                                                                \
      for (int c = 0; c < 4; c++) {                                                    \
        load_lds16(Aptr + (size_t)rowc[c] * DMODEL + k0 + 64 + colc[c], Asw + c * 2048 + wv * 512); \
        load_lds16(Bptr + (size_t)rowc[c] * DMODEL + k0 + 64 + colc[c], Bsw + c * 2048 + wv * 512); \
      }                                                                                \
    }                                                                                  \
    _Pragma("unroll")                                                                  \
    for (int kq = 0; kq < 2; kq++) {                                                   \
      const int cp = ((kq * 4 + quad) ^ swz) * 8;                                      \
      bf16x8 af[4], bfr[4];                                                            \
      _Pragma("unroll")                                                                \
      for (int rt = 0; rt < 4; rt++)                                                   \
        af[rt] = *(const bf16x8*)(Asr + (wr + rt * 16 + mi) * 64 + cp);                \
      _Pragma("unroll")                                                                \
      for (int ct = 0; ct < 4; ct++)                                                   \
        bfr[ct] = *(const bf16x8*)(Bsr + (wc + ct * 16 + mi) * 64 + cp);               \
      _Pragma("unroll")                                                                \
      for (int rt = 0; rt < 4; rt++)                                                   \
        _Pragma("unroll")                                                              \
        for (int ct = 0; ct < 4; ct++)                                                 \
          acc[rt][ct] = __builtin_amdgcn_mfma_f32_16x16x32_bf16(af[rt], bfr[ct], acc[rt][ct], 0, 0, 0); \
    }                                                                                  \
  }

// ---- fused QKV projection; Q prescaled by L2E_SCALE; K/V^T compacted ----
__global__ __launch_bounds__(256) void gemm_qkv(const unsigned short* __restrict__ A,
                                                const unsigned short* __restrict__ Wq,
                                                const unsigned short* __restrict__ Wkv,
                                                const int* __restrict__ pos,
                                                unsigned short* __restrict__ outQ,
                                                unsigned short* __restrict__ outK,
                                                unsigned short* __restrict__ outVt) {
  __shared__ alignas(16) unsigned short As[2 * 128 * 64];   // 32 KB
  __shared__ alignas(16) unsigned short Bs[2 * 128 * 64];   // 32 KB
  const int m0 = blockIdx.y * 128;
  const int n0 = blockIdx.x * 128;
  const unsigned short* Abase = A + (size_t)m0 * DMODEL;
  const unsigned short* Bbase = (n0 < DMODEL) ? (Wq + (size_t)n0 * DMODEL)
                                              : (Wkv + (size_t)(n0 - DMODEL) * DMODEL);
  GEMM64_DBUF(Abase, Bbase)

  const int region = n0 >> 10;  // uniform per block
#pragma unroll
  for (int rt = 0; rt < 4; rt++) {
#pragma unroll
    for (int r = 0; r < 4; r++) {
      const int gm = m0 + wr + rt * 16 + quad * 4 + r;
      const int i = gm >> 2, b = gm & 3;
      int p = i;
      if (region > 0) p = pos[b * T_LEN + i];
      if (region > 0 && p < 0) continue;   // masked key: drop
#pragma unroll
      for (int ct = 0; ct < 4; ct++) {
        const int gn = n0 + wc + ct * 16 + mi;
        const int gnl = gn & (DMODEL - 1);
        const int hn = gnl >> 6, d = gnl & 63;
        const float v = acc[rt][ct][r];
        if (region == 0)
          outQ[(((size_t)b * NHEAD + hn) * T_LEN + i) * DHEAD + d] = f2bf(v * L2E_SCALE);
        else if (region == 1)
          outK[(((size_t)b * NHEAD + hn) * T_LEN + p) * DHEAD + d] = f2bf(v);
        else
          outVt[(((size_t)b * NHEAD + hn) * DHEAD + d) * T_LEN + p] = f2bf(v);
      }
    }
  }
}

// ---- output projection: AV(8192x1024) * wo^T -> bf16 AO; 128x128, BK=64 dbuf ----
__global__ __launch_bounds__(256) void gemm_out(const unsigned short* __restrict__ A,
                                                const unsigned short* __restrict__ Bw,
                                                unsigned short* __restrict__ outB) {
  __shared__ alignas(16) unsigned short As[2 * 128 * 64];
  __shared__ alignas(16) unsigned short Bs[2 * 128 * 64];
  const int m0 = blockIdx.y * 128;
  const int n0 = blockIdx.x * 128;
  const unsigned short* Abase = A  + (size_t)m0 * DMODEL;
  const unsigned short* Bbase = Bw + (size_t)n0 * DMODEL;
  GEMM64_DBUF(Abase, Bbase)

#pragma unroll
  for (int rt = 0; rt < 4; rt++)
#pragma unroll
    for (int ct = 0; ct < 4; ct++)
#pragma unroll
      for (int r = 0; r < 4; r++) {
        const int gm = m0 + wr + rt * 16 + quad * 4 + r;
        const int gn = n0 + wc + ct * 16 + mi;
        outB[(size_t)gm * DMODEL + gn] = f2bf(acc[rt][ct][r]);
      }
}

// ---- attention chunk: S^T = K·Q^T (fixed-max exp2), P·V accumulate ----
// All LDS reads via swz16 layout (stride 64, granule XOR row&7).
// T5: setprio(1) around both MFMA clusters (attn +4-7%, m191).
template<bool TAIL>
__device__ __forceinline__ void attn_chunk(int j0, int nk, int mi, int quad,
    const unsigned short* Ks, const unsigned short* Vts, unsigned short* PsW,
    const bf16x8 (&qb)[2][2], f32x4 (&oc)[2][4], float (&rs)[2]) {
  f32x4 sc[2][4] = {};
  __builtin_amdgcn_s_setprio(1);
#pragma unroll
  for (int ct = 0; ct < 4; ct++) {
    const bf16x8 kf0 = *(const bf16x8*)(Ks + swz16(ct * 16 + mi, quad));
    const bf16x8 kf1 = *(const bf16x8*)(Ks + swz16(ct * 16 + mi, 4 + quad));
#pragma unroll
    for (int g = 0; g < 2; g++) {
      sc[g][ct] = __builtin_amdgcn_mfma_f32_16x16x32_bf16(kf0, qb[g][0], sc[g][ct], 0, 0, 0);
      sc[g][ct] = __builtin_amdgcn_mfma_f32_16x16x32_bf16(kf1, qb[g][1], sc[g][ct], 0, 0, 0);
    }
  }
  __builtin_amdgcn_s_setprio(0);
#pragma unroll
  for (int g = 0; g < 2; g++)
#pragma unroll
    for (int ct = 0; ct < 4; ct++) {
#pragma unroll
      for (int r = 0; r < 4; r++) {
        float p = __builtin_amdgcn_exp2f(sc[g][ct][r]);
        if (TAIL && (j0 + ct * 16 + quad * 4 + r >= nk)) p = 0.f;
        rs[g] += p;
        sc[g][ct][r] = p;
      }
      union { float f; unsigned u; } c0, c1, c2, c3;
      c0.f = sc[g][ct][0]; c1.f = sc[g][ct][1]; c2.f = sc[g][ct][2]; c3.f = sc[g][ct][3];
      const unsigned pk0 = (c0.u >> 16) | (c1.u & 0xFFFF0000u);   // bf16 trunc pack
      const unsigned pk1 = (c2.u >> 16) | (c3.u & 0xFFFF0000u);
      const int prow = g * 16 + mi;
      // col = ct*16 + quad*4 -> granule 2ct+(quad>>1), sub (quad&1)*4 shorts
      *(uint2*)(PsW + prow * 64 + (((2 * ct + (quad >> 1)) ^ (prow & 7)) << 3)
                + (quad & 1) * 4) = make_uint2(pk0, pk1);
    }
  bf16x8 pa0[2], pa1[2];
#pragma unroll
  for (int g = 0; g < 2; g++) {
    pa0[g] = *(const bf16x8*)(PsW + swz16(g * 16 + mi, quad));
    pa1[g] = *(const bf16x8*)(PsW + swz16(g * 16 + mi, 4 + quad));
  }
  __builtin_amdgcn_s_setprio(1);
#pragma unroll
  for (int ct = 0; ct < 4; ct++) {
    const bf16x8 vf0 = *(const bf16x8*)(Vts + swz16(ct * 16 + mi, quad));
    const bf16x8 vf1 = *(const bf16x8*)(Vts + swz16(ct * 16 + mi, 4 + quad));
#pragma unroll
    for (int g = 0; g < 2; g++) {
      oc[g][ct] = __builtin_amdgcn_mfma_f32_16x16x32_bf16(pa0[g], vf0, oc[g][ct], 0, 0, 0);
      oc[g][ct] = __builtin_amdgcn_mfma_f32_16x16x32_bf16(pa1[g], vf1, oc[g][ct], 0, 0, 0);
    }
  }
  __builtin_amdgcn_s_setprio(0);
}

// async double-buffered K/V staging via global_load_lds: linear LDS dest
// (wave-uniform base + lane*16), inverse-swizzled global source (rule #21).
__device__ __forceinline__ void stage_kv(const unsigned short* __restrict__ Kg,
                                         const unsigned short* __restrict__ Vtg,
                                         size_t base, int j0s, unsigned short* kb,
                                         int tid, int wv) {
#pragma unroll
  for (int u = 0; u < 2; u++) {
    const int gi = u * 256 + tid;        // 16B granule index 0..511
    const int r = gi >> 3;               // row (K: key row / V: d row)
    const int gs = (gi ^ r) & 7;         // inverse-swizzled logical granule
    load_lds16(Kg + base + (size_t)(j0s + r) * DHEAD + gs * 8,
               kb + u * 2048 + wv * 512);
    load_lds16(Vtg + base + (size_t)r * T_LEN + j0s + gs * 8,
               kb + 4096 + u * 2048 + wv * 512);
  }
}

// grid 1D(1024) = (T/128) x B x NH, XCD-affinity decode: all 16 q-tiles of one
// (b,n) pair land on bids congruent mod 8 -> same XCD under round-robin mapping
// -> K/V fetched from HBM once per pair, L2-hit for the other 15 blocks (T1).
// 256 thr = 4 waves x 32 q-rows. K/V double-buffered via global_load_lds; ONE
// barrier per chunk (m97 schedule).
__global__ __launch_bounds__(256, 3) void attn_mfma(const unsigned short* __restrict__ Qg,
                                                    const unsigned short* __restrict__ Kg,
                                                    const unsigned short* __restrict__ Vtg,
                                                    const int* __restrict__ nkeys,
                                                    unsigned short* __restrict__ av) {
  // buf p: K at p*8192, V at p*8192+4096 (shorts); Qs/PsW at 16384; Ls at 24576
  __shared__ alignas(16) unsigned short smem[24832];
  unsigned short* Qs = smem + 16384;
  float* Ls = (float*)(smem + 24576);

  const int tid  = threadIdx.x;
  const int lane = tid & 63;
  const int wv   = tid >> 6;
  const int mi   = lane & 15;
  const int quad = lane >> 4;
  // XCD-affinity decode (bijective): pair p owns bids {p&7 + 8*((p>>3)*16+q)}
  const int bid = blockIdx.x;
  const int p   = ((bid >> 7) << 3) | (bid & 7);   // (b,n) pair 0..63
  const int i0  = ((bid >> 3) & 15) * 128;         // q-tile
  const int b   = p >> 4;
  const int n   = p & 15;
  const size_t base = ((size_t)b * NHEAD + n) * T_LEN * DHEAD;
  const int nk = nkeys[b];
  const int nc = (nk + 63) >> 6;

  for (int it = tid; it < 1024; it += 256) {
    const int r = it >> 3, g = it & 7;
    *(uint4*)(Qs + swz16(r, g)) = *(const uint4*)(Qg + base + (size_t)(i0 + r) * DHEAD + g * 8);
  }
  if (nc > 0) stage_kv(Kg, Vtg, base, 0, smem, tid, wv);
  __syncthreads();
  bf16x8 qb[2][2];
#pragma unroll
  for (int g = 0; g < 2; g++) {
    qb[g][0] = *(const bf16x8*)(Qs + swz16(wv * 32 + g * 16 + mi, quad));
    qb[g][1] = *(const bf16x8*)(Qs + swz16(wv * 32 + g * 16 + mi, 4 + quad));
  }

  f32x4 oc[2][4] = {};
  float rs[2] = {0.f, 0.f};
  unsigned short* PsW = Qs + wv * 2048;   // 32 rows x 64 per wave (own q-rows; disjoint)

  for (int c = 0; c < nc; ++c) {
    if (c + 1 < nc) stage_kv(Kg, Vtg, base, (c + 1) * 64, smem + ((c + 1) & 1) * 8192, tid, wv);
    const unsigned short* Kl = smem + (c & 1) * 8192;
    const unsigned short* Vl = Kl + 4096;
    if (c == nc - 1 && (nk & 63))
      attn_chunk<true>(c * 64, nk, mi, quad, Kl, Vl, PsW, qb, oc, rs);
    else
      attn_chunk<false>(c * 64, nk, mi, quad, Kl, Vl, PsW, qb, oc, rs);
    __syncthreads();   // drains staged loads (vmcnt0) + all waves done with Kl/Vl
  }

#pragma unroll
  for (int g = 0; g < 2; g++) {
    float t = rs[g];
    t += __shfl_xor(t, 16, 64);
    t += __shfl_xor(t, 32, 64);
    rs[g] = t;
  }
  if (quad == 0) { Ls[wv * 32 + mi] = rs[0]; Ls[wv * 32 + 16 + mi] = rs[1]; }
  __syncthreads();
  float linv[2][4];
#pragma unroll
  for (int g = 0; g < 2; g++)
#pragma unroll
    for (int r = 0; r < 4; r++) {
      const float l = Ls[wv * 32 + g * 16 + quad * 4 + r];
      linv[g][r] = (l > 0.f) ? (1.f / l) : 0.f;
    }
#pragma unroll
  for (int g = 0; g < 2; g++)
#pragma unroll
    for (int ct = 0; ct < 4; ct++)
#pragma unroll
      for (int r = 0; r < 4; r++) {
        const int q = i0 + wv * 32 + g * 16 + quad * 4 + r;
        const int d = ct * 16 + mi;
        av[((size_t)q * BSZ + b) * DMODEL + n * DHEAD + d] = f2bf(oc[g][ct][r] * linv[g][r]);
      }
}

// ---- out = LayerNorm(h + attn_out)*g + b : wave-per-row, zero barriers ----
// grid 2048 x 256 thr = 4 waves = 4 rows/block; lane holds 16 cols (4x float4).
__global__ __launch_bounds__(256) void ln_kernel(const float* __restrict__ h,
                                                 const unsigned short* __restrict__ ao,
                                                 const float* __restrict__ g,
                                                 const float* __restrict__ bb,
                                                 float* __restrict__ out) {
  const int tid = threadIdx.x, lane = tid & 63, wv = tid >> 6;
  const int row = blockIdx.x * 4 + wv;
  const size_t base = (size_t)row * DMODEL;
  float x[16];
  float s = 0.f, sq = 0.f;
#pragma unroll
  for (int k = 0; k < 4; k++) {
    const int c = lane * 4 + k * 256;
    const float4 hv = *(const float4*)(h + base + c);
    const ushort4 a4 = *(const ushort4*)(ao + base + c);
    x[k * 4 + 0] = hv.x + bf2f(a4.x);
    x[k * 4 + 1] = hv.y + bf2f(a4.y);
    x[k * 4 + 2] = hv.z + bf2f(a4.z);
    x[k * 4 + 3] = hv.w + bf2f(a4.w);
#pragma unroll
    for (int j = 0; j < 4; j++) { s += x[k * 4 + j]; sq += x[k * 4 + j] * x[k * 4 + j]; }
  }
#pragma unroll
  for (int off = 32; off; off >>= 1) { s += __shfl_xor(s, off, 64); sq += __shfl_xor(sq, off, 64); }
  const float mu  = s * (1.f / DMODEL);
  const float var = sq * (1.f / DMODEL) - mu * mu;
  const float inv = rsqrtf(var + 1e-5f);
#pragma unroll
  for (int k = 0; k < 4; k++) {
    const int c = lane * 4 + k * 256;
    const float4 gv = *(const float4*)(g + c);
    const float4 bv = *(const float4*)(bb + c);
    float4 o;
    o.x = (x[k * 4 + 0] - mu) * inv * gv.x + bv.x;
    o.y = (x[k * 4 + 1] - mu) * inv * gv.y + bv.y;
    o.z = (x[k * 4 + 2] - mu) * inv * gv.z + bv.z;
    o.w = (x[k * 4 + 3] - mu) * inv * gv.w + bv.w;
    *(float4*)(out + base + c) = o;
  }
}

extern "C" void kernel_launch(void* const* d_in, const int* in_sizes, int n_in,
                              void* d_out, int out_size, void* d_ws, size_t ws_size,
                              hipStream_t stream) {
  (void)in_sizes; (void)n_in; (void)out_size; (void)ws_size;
  const float* h           = (const float*)d_in[0];
  const unsigned char* msk = (const unsigned char*)d_in[1];
  const float* wq          = (const float*)d_in[2];
  const float* wkv         = (const float*)d_in[3];
  const float* wo          = (const float*)d_in[4];
  const float* lng         = (const float*)d_in[5];
  const float* lnb         = (const float*)d_in[6];
  float* out = (float*)d_out;

  const size_t E  = (size_t)T_LEN * BSZ * DMODEL;        // 8.39M
  const size_t WQ = (size_t)NHEAD * DHEAD * DMODEL;      // 1.05M
  char* ws = (char*)d_ws;
  int* nkeys            = (int*)ws;                       ws += 16;
  int* pos              = (int*)ws;                       ws += (size_t)BSZ * T_LEN * 4;
  unsigned short* h_bf  = (unsigned short*)ws;            ws += E * 2;
  unsigned short* wq_bf = (unsigned short*)ws;            ws += WQ * 2;
  unsigned short* wkv_bf= (unsigned short*)ws;            ws += 2 * WQ * 2;
  unsigned short* wo_bf = (unsigned short*)ws;            ws += WQ * 2;
  unsigned short* Qb    = (unsigned short*)ws;            ws += E * 2;
  unsigned short* Kb    = (unsigned short*)ws;            ws += E * 2;
  unsigned short* Vtb   = (unsigned short*)ws;            ws += E * 2;
  unsigned short* AV    = (unsigned short*)ws;            ws += E * 2;
  unsigned short* AO    = (unsigned short*)ws;

  const dim3 blk(256);
  cvt_prep<<<dim3(12289), blk, 0, stream>>>(h, wq, wkv, wo, msk,
                                            h_bf, wq_bf, wkv_bf, wo_bf, pos, nkeys);
  gemm_qkv<<<dim3(3 * DMODEL / 128, T_LEN * BSZ / 128), blk, 0, stream>>>(
      h_bf, wq_bf, wkv_bf, pos, Qb, Kb, Vtb);
  attn_mfma<<<dim3(1024), blk, 0, stream>>>(Qb, Kb, Vtb, nkeys, AV);
  gemm_out<<<dim3(DMODEL / 128, T_LEN * BSZ / 128), blk, 0, stream>>>(AV, wo_bf, AO);
  ln_kernel<<<dim3(T_LEN * BSZ / 4), blk, 0, stream>>>(h, AO, lng, lnb, out);
}